// Round 1
// baseline (3331.877 us; speedup 1.0000x reference)
//
#include <hip/hip_runtime.h>

// Fused retention block: one 512-thread workgroup per location n (N=8192).
// Per block: X tile is 32x128; QKV proj -> rotary -> attention over S=32
// -> LN1 -> FFN(128->512->128) -> LN2 -> transposed store.
// LDS: Q|K|V each [32][129] fp32 (odd stride = bank-conflict-free), 49.5 KB.
// FFN hidden (16x512 per half) aliases the dead K/V region.

#define NN 8192   // locations (grid)
#define BS 32     // S = B frames (attention length)
#define CC 128    // embed
#define HH 8      // heads
#define DD 16     // head dim
#define FF 512    // ffn hidden
#define QS 129    // padded LDS row stride (floats)

__global__ __launch_bounds__(512, 4) void fused_retention_block(
    const float* __restrict__ x,
    const float* __restrict__ wq, const float* __restrict__ bq,
    const float* __restrict__ wk, const float* __restrict__ bk,
    const float* __restrict__ wv, const float* __restrict__ bv,
    const float* __restrict__ ln1g, const float* __restrict__ ln1b,
    const float* __restrict__ w1, const float* __restrict__ b1,
    const float* __restrict__ w2, const float* __restrict__ b2,
    const float* __restrict__ ln2g, const float* __restrict__ ln2b,
    float* __restrict__ out)
{
  const int n = blockIdx.x;
  const int t = threadIdx.x;

  __shared__ float SM[3 * BS * QS];   // Qs | Ks | Vs ; K/V region reused as FFN hidden
  float* Qs = SM;
  float* Ks = SM + BS * QS;
  float* Vs = SM + 2 * BS * QS;

  // ---------------- Phase B: Q,K,V = xt[n] @ W + b -------------------------
  // thread t: output columns o4*4..o4*4+3, rows 2*sp and 2*sp+1
  {
    const int o4 = t & 31;
    const int sp = t >> 5;                       // 0..15
    const float* xr0 = x + ((size_t)(2 * sp) * NN + n) * CC;
    const float* xr1 = xr0 + (size_t)NN * CC;
    for (int m = 0; m < 3; ++m) {
      const float* W  = (m == 0) ? wq : (m == 1) ? wk : wv;
      const float* bb = (m == 0) ? bq : (m == 1) ? bk : bv;
      float* O = SM + m * BS * QS;
      float b4[4];
      *(float4*)b4 = *(const float4*)(bb + o4 * 4);
      float a0[4] = {b4[0], b4[1], b4[2], b4[3]};
      float a1[4] = {b4[0], b4[1], b4[2], b4[3]};
      for (int c4 = 0; c4 < 32; ++c4) {
        float xa4[4], xb4[4];
        *(float4*)xa4 = *(const float4*)(xr0 + c4 * 4);
        *(float4*)xb4 = *(const float4*)(xr1 + c4 * 4);
        const float* wp = W + (c4 * 4) * CC + o4 * 4;
        #pragma unroll
        for (int j = 0; j < 4; ++j) {
          float w4[4];
          *(float4*)w4 = *(const float4*)(wp + j * CC);
          #pragma unroll
          for (int e = 0; e < 4; ++e) {
            a0[e] += xa4[j] * w4[e];
            a1[e] += xb4[j] * w4[e];
          }
        }
      }
      float* q0 = O + (2 * sp) * QS + o4 * 4;
      float* q1 = O + (2 * sp + 1) * QS + o4 * 4;
      #pragma unroll
      for (int e = 0; e < 4; ++e) { q0[e] = a0[e]; q1[e] = a1[e]; }
    }
  }
  __syncthreads();

  // ---------------- Phase B2: rotary on Q (t<256) and K (t>=256) -----------
  {
    const int tt = t & 255;
    const int s = tt >> 3;                       // 0..31
    const int h = tt & 7;
    float* row = ((t < 256) ? Qs : Ks) + s * QS + h * DD;
    float v[DD];
    #pragma unroll
    for (int d = 0; d < DD; ++d) v[d] = row[d];
    #pragma unroll
    for (int d = 0; d < DD; ++d) {
      const int j = d >> 1;
      // angle[d] = 10000^(-(d/2)/7) = exp2(-log2(1e4)/7 * j)
      const float a = exp2f(-1.89824462565f * (float)j);
      const float ang = (float)s * a;
      const float sn = sinf(ang);
      const float cs = cosf(ang);
      const float rot = (d < 8) ? -v[2 * d + 1] : v[2 * (d - 8)];
      row[d] = v[d] * cs + rot * sn;
    }
  }
  __syncthreads();

  // ---------------- Phase C: attention per (h, qi), t < 256 ----------------
  if (t < 256) {
    const int h = t >> 5;
    const int qi = t & 31;
    const float dec = log1pf(-exp2f(-(1.0f + 0.375f * (float)h)));
    float q[DD];
    const float* Qr = Qs + qi * QS + h * DD;
    #pragma unroll
    for (int d = 0; d < DD; ++d) q[d] = Qr[d];

    float sc[BS];
    float mx = -3.0e38f;
    #pragma unroll
    for (int jj = 0; jj < BS; ++jj) {
      const float* Kr = Ks + jj * QS + h * DD;
      float acc = fabsf((float)(qi - jj)) * dec;
      #pragma unroll
      for (int d = 0; d < DD; ++d) acc += q[d] * Kr[d];
      sc[jj] = acc;
      mx = fmaxf(mx, acc);
    }
    float sum = 0.0f;
    #pragma unroll
    for (int jj = 0; jj < BS; ++jj) {
      const float p = __expf(sc[jj] - mx);
      sc[jj] = p;
      sum += p;
    }
    const float inv = 1.0f / sum;
    float o[DD];
    #pragma unroll
    for (int d = 0; d < DD; ++d) o[d] = 0.0f;
    #pragma unroll
    for (int jj = 0; jj < BS; ++jj) {
      const float p = sc[jj] * inv;
      const float* Vr = Vs + jj * QS + h * DD;
      #pragma unroll
      for (int d = 0; d < DD; ++d) o[d] += p * Vr[d];
    }
    // write attn-out over own Q slice (no other thread touches it)
    float* Od = Qs + qi * QS + h * DD;
    #pragma unroll
    for (int d = 0; d < DD; ++d) Od[d] = o[d];
  }
  __syncthreads();

  // ---------------- Phase D: LN1( attn_out + xt ), in place in Qs ----------
  {
    const int row = t >> 4;                      // 0..31
    const int sub = t & 15;                      // 16 threads/row, 8 cols each
    float* Orow = Qs + row * QS + sub * 8;
    const float* xrow = x + ((size_t)row * NN + n) * CC + sub * 8;
    float v[8];
    #pragma unroll
    for (int i = 0; i < 8; ++i) v[i] = Orow[i] + xrow[i];
    float sum = 0.0f;
    #pragma unroll
    for (int i = 0; i < 8; ++i) sum += v[i];
    #pragma unroll
    for (int m = 1; m < 16; m <<= 1) sum += __shfl_xor(sum, m);
    const float mu = sum * (1.0f / 128.0f);
    float s2 = 0.0f;
    #pragma unroll
    for (int i = 0; i < 8; ++i) { const float d = v[i] - mu; s2 += d * d; }
    #pragma unroll
    for (int m = 1; m < 16; m <<= 1) s2 += __shfl_xor(s2, m);
    const float rstd = rsqrtf(s2 * (1.0f / 128.0f) + 1e-5f);
    #pragma unroll
    for (int i = 0; i < 8; ++i) {
      const int c = sub * 8 + i;
      Orow[i] = (v[i] - mu) * rstd * ln1g[c] + ln1b[c];
    }
  }
  __syncthreads();

  // ---------------- Phase E/F: FFN in two 16-row halves --------------------
  // Hidden H[16][512] lives in the (dead) Ks..Vs region.
  float* Hb = Ks;
  const int f4  = t & 127;                        // hidden quad col
  const int sb4 = (t >> 7) * 4;                   // 4 local rows per thread
  const int o4f = t & 31;                         // out quad col (phase F)
  const int sF  = t >> 5;                         // local row (phase F)

  for (int p = 0; p < 2; ++p) {
    // Phase E: H = relu(O1 @ w1 + b1) for rows p*16 .. p*16+15
    {
      float acc[4][4];
      float b14[4];
      *(float4*)b14 = *(const float4*)(b1 + f4 * 4);
      #pragma unroll
      for (int i = 0; i < 4; ++i)
        #pragma unroll
        for (int e = 0; e < 4; ++e) acc[i][e] = b14[e];
      const float* O1b = Qs + (p * 16 + sb4) * QS;
      for (int c = 0; c < CC; ++c) {
        float w4[4];
        *(float4*)w4 = *(const float4*)(w1 + c * FF + f4 * 4);
        #pragma unroll
        for (int i = 0; i < 4; ++i) {
          const float xv = O1b[i * QS + c];
          #pragma unroll
          for (int e = 0; e < 4; ++e) acc[i][e] += xv * w4[e];
        }
      }
      #pragma unroll
      for (int i = 0; i < 4; ++i) {
        float4 r;
        r.x = fmaxf(acc[i][0], 0.0f);
        r.y = fmaxf(acc[i][1], 0.0f);
        r.z = fmaxf(acc[i][2], 0.0f);
        r.w = fmaxf(acc[i][3], 0.0f);
        *(float4*)(Hb + (sb4 + i) * FF + f4 * 4) = r;
      }
    }
    __syncthreads();

    // Phase F: out2 = H @ w2 + b2 + O1 ; LN2 via 32-lane shuffle; store
    {
      const int s = p * 16 + sF;
      float acc[4];
      *(float4*)acc = *(const float4*)(b2 + o4f * 4);
      const float* hrow = Hb + sF * FF;
      for (int k = 0; k < FF; ++k) {
        const float hv = hrow[k];
        float w4[4];
        *(float4*)w4 = *(const float4*)(w2 + k * CC + o4f * 4);
        #pragma unroll
        for (int e = 0; e < 4; ++e) acc[e] += hv * w4[e];
      }
      const float* res = Qs + s * QS + o4f * 4;   // odd stride: scalar reads
      #pragma unroll
      for (int e = 0; e < 4; ++e) acc[e] += res[e];

      // LN2: 32 lanes share row s (lanes t&31 within half-wave)
      float sum = acc[0] + acc[1] + acc[2] + acc[3];
      #pragma unroll
      for (int m = 1; m < 32; m <<= 1) sum += __shfl_xor(sum, m);
      const float mu = sum * (1.0f / 128.0f);
      float s2 = 0.0f;
      #pragma unroll
      for (int e = 0; e < 4; ++e) { const float d = acc[e] - mu; s2 += d * d; }
      #pragma unroll
      for (int m = 1; m < 32; m <<= 1) s2 += __shfl_xor(s2, m);
      const float rstd = rsqrtf(s2 * (1.0f / 128.0f) + 1e-5f);

      float4 r;
      const int c0 = o4f * 4;
      r.x = (acc[0] - mu) * rstd * ln2g[c0 + 0] + ln2b[c0 + 0];
      r.y = (acc[1] - mu) * rstd * ln2g[c0 + 1] + ln2b[c0 + 1];
      r.z = (acc[2] - mu) * rstd * ln2g[c0 + 2] + ln2b[c0 + 2];
      r.w = (acc[3] - mu) * rstd * ln2g[c0 + 3] + ln2b[c0 + 3];
      // out[s][n][c] (output is (B=S, N, C))
      *(float4*)(out + ((size_t)s * NN + n) * CC + c0) = r;
    }
    __syncthreads();   // protect Hb before next half's writes
  }
}

extern "C" void kernel_launch(void* const* d_in, const int* in_sizes, int n_in,
                              void* d_out, int out_size, void* d_ws, size_t ws_size,
                              hipStream_t stream) {
  (void)in_sizes; (void)n_in; (void)d_ws; (void)ws_size; (void)out_size;
  const float* x    = (const float*)d_in[0];
  const float* wq   = (const float*)d_in[1];
  const float* bq_  = (const float*)d_in[2];
  const float* wk   = (const float*)d_in[3];
  const float* bk_  = (const float*)d_in[4];
  const float* wv   = (const float*)d_in[5];
  const float* bv_  = (const float*)d_in[6];
  const float* ln1g = (const float*)d_in[7];
  const float* ln1b = (const float*)d_in[8];
  const float* w1   = (const float*)d_in[9];
  const float* b1   = (const float*)d_in[10];
  const float* w2   = (const float*)d_in[11];
  const float* b2   = (const float*)d_in[12];
  const float* ln2g = (const float*)d_in[13];
  const float* ln2b = (const float*)d_in[14];
  float* outp = (float*)d_out;

  fused_retention_block<<<NN, 512, 0, stream>>>(
      x, wq, bq_, wk, bk_, wv, bv_, ln1g, ln1b,
      w1, b1, w2, b2, ln2g, ln2b, outp);
}

// Round 2
// 631.844 us; speedup vs baseline: 5.2733x; 5.2733x over previous
//
#include <hip/hip_runtime.h>

// Fused retention block, MFMA edition.
// grid = 8192 blocks (one per location n), 512 threads = 8 waves.
// Phases: stage x->bf16 LDS | QKV via mfma_16x16x32_bf16 | rotary | attention
// (fp32 scalar) | LN1 | 2x( FFN1-half mfma, FFN2-half mfma, LN2+store ).
// Weights pre-packed to bf16 MFMA B-fragment order in d_ws by pack_weights.

#define NN 8192
#define BS 32
#define CC 128
#define HH 8
#define DD 16
#define FF 512
#define QS 129   // legacy fp32 fallback stride

typedef __attribute__((ext_vector_type(8))) short bf16x8;
typedef __attribute__((ext_vector_type(4))) float f32x4;
typedef __attribute__((ext_vector_type(4))) unsigned int u32x4;

__device__ inline unsigned short f2bf(float f) {
  unsigned u = __builtin_bit_cast(unsigned, f);
  u = (u + 0x7FFFu + ((u >> 16) & 1u)) >> 16;
  return (unsigned short)u;
}
__device__ inline float bf2f(unsigned short h) {
  unsigned u = ((unsigned)h) << 16;
  return __builtin_bit_cast(float, u);
}

// ---------------------------------------------------------------------------
// Pack kernel: weights -> bf16 fragments. Chunk = one wave-load of 64x16B.
// chunks 0..95   : QKV  (ct 0..23 over wq|wk|wv, kk 0..3)   chunk = ct*4+kk
// chunks 96..223 : w1   (ct 0..31, kk 0..3)                  96 + ct*4+kk
// chunks 224..351: w2   (ct 0..7,  kk 0..15)                 224 + ct*16+kk
// lane l of chunk holds B[k0+j][col], k0 = kk*32+(l>>4)*8, col = ct*16+(l&15)
// ---------------------------------------------------------------------------
__global__ void pack_weights(const float* __restrict__ wq, const float* __restrict__ wk,
                             const float* __restrict__ wv, const float* __restrict__ w1,
                             const float* __restrict__ w2, unsigned short* __restrict__ outp)
{
  const int id = blockIdx.x * 256 + threadIdx.x;
  if (id >= 22528) return;
  const int l = id & 63;
  const int chunk = id >> 6;
  const float* W; int ldw, colbase, k0;
  if (chunk < 96) {
    const int ct = chunk >> 2, kk = chunk & 3;
    W = (ct < 8) ? wq : (ct < 16) ? wk : wv;
    ldw = CC; colbase = (ct & 7) * 16 + (l & 15); k0 = kk * 32 + (l >> 4) * 8;
  } else if (chunk < 224) {
    const int c2 = chunk - 96, ct = c2 >> 2, kk = c2 & 3;
    W = w1; ldw = FF; colbase = ct * 16 + (l & 15); k0 = kk * 32 + (l >> 4) * 8;
  } else {
    const int c2 = chunk - 224, ct = c2 >> 4, kk = c2 & 15;
    W = w2; ldw = CC; colbase = ct * 16 + (l & 15); k0 = kk * 32 + (l >> 4) * 8;
  }
  unsigned int o[4];
  #pragma unroll
  for (int jj = 0; jj < 4; ++jj) {
    const unsigned lo = f2bf(W[(size_t)(k0 + 2 * jj) * ldw + colbase]);
    const unsigned hi = f2bf(W[(size_t)(k0 + 2 * jj + 1) * ldw + colbase]);
    o[jj] = lo | (hi << 16);
  }
  *(u32x4*)(outp + (size_t)id * 8) = (u32x4){o[0], o[1], o[2], o[3]};
}

// ---------------------------------------------------------------------------
// Fused kernel. LDS map (bytes):
//   [0,8704)      Xb  bf16[32][136]   (x tile; residual for LN1)  | FFN: H bf16[16][552] = [0,17664)
//   [8704,25600)  Qf  f32[32][132]    (Q; then attn-out O)        |      (tail of H)
//   [25600,42496) Kf  f32[32][132]    (K; then O1 = LN1 out fp32)
//   [42496,51200) Vf->A2b bf16[32][136] region start (V f32 uses [42496,59392) in QKV phase)
//   [51200,59648) O2  f32[16][132]    (FFN2-half out, LN2 input)
// Pool = 59648 B. Note Vf f32[32][132] spans [42496,59392) during QKV/attn;
// O2 region only live in FFN phase (after V dead). 2 blocks/CU by LDS.
// ---------------------------------------------------------------------------
#define XB_OFF 0
#define QF_OFF 8704
#define KF_OFF 25600
#define VF_OFF 42496
#define O2_OFF 51200
#define H_OFF  0
#define LDS_BYTES 59648

__global__ __launch_bounds__(512, 2) void fused_mfma(
    const float* __restrict__ x,
    const float* __restrict__ bq, const float* __restrict__ bk, const float* __restrict__ bv,
    const float* __restrict__ ln1g, const float* __restrict__ ln1b,
    const float* __restrict__ b1, const float* __restrict__ b2,
    const float* __restrict__ ln2g, const float* __restrict__ ln2b,
    const unsigned short* __restrict__ wpack,
    float* __restrict__ out)
{
  extern __shared__ char smem[];
  float* ldsf = (float*)smem;
  unsigned short* ldsh = (unsigned short*)smem;
  const int n = blockIdx.x;
  const int t = threadIdx.x;
  const int w = t >> 6;
  const int l = t & 63;
  const int lr = l & 15;
  const int lg = l >> 4;

  // ---------------- stage X -> bf16 LDS (coalesced 32B/thread) -------------
  {
    const int s = t >> 4, c0 = (t & 15) * 8;
    const float* xp = x + ((size_t)s * NN + n) * CC + c0;
    const float4 v0 = *(const float4*)xp;
    const float4 v1 = *(const float4*)(xp + 4);
    u32x4 pk;
    pk[0] = (unsigned)f2bf(v0.x) | ((unsigned)f2bf(v0.y) << 16);
    pk[1] = (unsigned)f2bf(v0.z) | ((unsigned)f2bf(v0.w) << 16);
    pk[2] = (unsigned)f2bf(v1.x) | ((unsigned)f2bf(v1.y) << 16);
    pk[3] = (unsigned)f2bf(v1.z) | ((unsigned)f2bf(v1.w) << 16);
    *(u32x4*)(ldsh + XB_OFF / 2 + s * 136 + c0) = pk;
  }
  __syncthreads();

  // ---------------- QKV: 32x384 = 8 waves x (2 rowtiles x 3 coltiles) ------
  {
    f32x4 acc[2][3];
    #pragma unroll
    for (int c = 0; c < 3; ++c) {
      const int ct = 3 * w + c;
      const int col = (ct & 7) * 16 + lr;
      const float* bb = (ct < 8) ? bq : (ct < 16) ? bk : bv;
      const float b = bb[col];
      acc[0][c] = (f32x4){b, b, b, b};
      acc[1][c] = acc[0][c];
    }
    #pragma unroll
    for (int kk = 0; kk < 4; ++kk) {
      const bf16x8 a0 = *(const bf16x8*)(ldsh + XB_OFF / 2 + lr * 136 + kk * 32 + lg * 8);
      const bf16x8 a1 = *(const bf16x8*)(ldsh + XB_OFF / 2 + (16 + lr) * 136 + kk * 32 + lg * 8);
      #pragma unroll
      for (int c = 0; c < 3; ++c) {
        const int ct = 3 * w + c;
        const bf16x8 b = *(const bf16x8*)(wpack + ((size_t)(ct * 4 + kk) * 64 + l) * 8);
        acc[0][c] = __builtin_amdgcn_mfma_f32_16x16x32_bf16(a0, b, acc[0][c], 0, 0, 0);
        acc[1][c] = __builtin_amdgcn_mfma_f32_16x16x32_bf16(a1, b, acc[1][c], 0, 0, 0);
      }
    }
    #pragma unroll
    for (int c = 0; c < 3; ++c) {
      const int ct = 3 * w + c;
      const int roff = (ct < 8) ? QF_OFF / 4 : (ct < 16) ? KF_OFF / 4 : VF_OFF / 4;
      const int col = (ct & 7) * 16 + lr;
      #pragma unroll
      for (int rt = 0; rt < 2; ++rt)
        #pragma unroll
        for (int e = 0; e < 4; ++e)
          ldsf[roff + (rt * 16 + lg * 4 + e) * 132 + col] = acc[rt][c][e];
    }
  }
  __syncthreads();

  // ---------------- rotary on Q (t<256) and K (t>=256), fp32 ---------------
  {
    const int tt = t & 255;
    const int s = tt >> 3, h = tt & 7;
    float* row = ldsf + ((t < 256) ? QF_OFF / 4 : KF_OFF / 4) + s * 132 + h * DD;
    float v[DD];
    #pragma unroll
    for (int d = 0; d < DD; ++d) v[d] = row[d];
    #pragma unroll
    for (int d = 0; d < DD; ++d) {
      const int j = d >> 1;
      const float a = exp2f(-1.89824462565f * (float)j);
      const float ang = (float)s * a;
      const float sn = sinf(ang);
      const float cs = cosf(ang);
      const float rot = (d < 8) ? -v[2 * d + 1] : v[2 * (d - 8)];
      row[d] = v[d] * cs + rot * sn;
    }
  }
  __syncthreads();

  // ---------------- attention per (h, qi), t < 256, fp32 -------------------
  if (t < 256) {
    const int h = t >> 5;
    const int qi = t & 31;
    const float dec = log1pf(-exp2f(-(1.0f + 0.375f * (float)h)));
    float q[DD];
    const float* Qr = ldsf + QF_OFF / 4 + qi * 132 + h * DD;
    #pragma unroll
    for (int d = 0; d < DD; ++d) q[d] = Qr[d];
    float sc[BS];
    float mx = -3.0e38f;
    #pragma unroll
    for (int jj = 0; jj < BS; ++jj) {
      const float* Kr = ldsf + KF_OFF / 4 + jj * 132 + h * DD;
      float acc = fabsf((float)(qi - jj)) * dec;
      #pragma unroll
      for (int d = 0; d < DD; ++d) acc += q[d] * Kr[d];
      sc[jj] = acc;
      mx = fmaxf(mx, acc);
    }
    float sum = 0.0f;
    #pragma unroll
    for (int jj = 0; jj < BS; ++jj) {
      const float p = __expf(sc[jj] - mx);
      sc[jj] = p;
      sum += p;
    }
    const float inv = 1.0f / sum;
    float o[DD];
    #pragma unroll
    for (int d = 0; d < DD; ++d) o[d] = 0.0f;
    #pragma unroll
    for (int jj = 0; jj < BS; ++jj) {
      const float p = sc[jj] * inv;
      const float* Vr = ldsf + VF_OFF / 4 + jj * 132 + h * DD;
      #pragma unroll
      for (int d = 0; d < DD; ++d) o[d] += p * Vr[d];
    }
    float* Od = ldsf + QF_OFF / 4 + qi * 132 + h * DD;
    #pragma unroll
    for (int d = 0; d < DD; ++d) Od[d] = o[d];
  }
  __syncthreads();

  // ---------------- LN1(attn_out + x); O1 fp32 -> Kf, bf16 -> A2b(Vf) ------
  {
    const int row = t >> 4, sub = t & 15;
    const float* Orow = ldsf + QF_OFF / 4 + row * 132 + sub * 8;
    const unsigned short* xrow = ldsh + XB_OFF / 2 + row * 136 + sub * 8;
    float v[8];
    #pragma unroll
    for (int i = 0; i < 8; ++i) v[i] = Orow[i] + bf2f(xrow[i]);
    float sum = 0.0f;
    #pragma unroll
    for (int i = 0; i < 8; ++i) sum += v[i];
    #pragma unroll
    for (int m = 1; m < 16; m <<= 1) sum += __shfl_xor(sum, m);
    const float mu = sum * (1.0f / 128.0f);
    float s2 = 0.0f;
    #pragma unroll
    for (int i = 0; i < 8; ++i) { const float d = v[i] - mu; s2 += d * d; }
    #pragma unroll
    for (int m = 1; m < 16; m <<= 1) s2 += __shfl_xor(s2, m);
    const float rstd = rsqrtf(s2 * (1.0f / 128.0f) + 1e-5f);
    u32x4 pk;
    float o8[8];
    #pragma unroll
    for (int i = 0; i < 8; ++i) {
      const int c = sub * 8 + i;
      o8[i] = (v[i] - mu) * rstd * ln1g[c] + ln1b[c];
    }
    __syncthreads();   // all reads of Qf(O)/Xb done before O1 overwrites Kf? (Kf write below; Qf/Xb only read above)
    #pragma unroll
    for (int i = 0; i < 8; ++i)
      ldsf[KF_OFF / 4 + row * 132 + sub * 8 + i] = o8[i];
    #pragma unroll
    for (int i = 0; i < 4; ++i)
      pk[i] = (unsigned)f2bf(o8[2 * i]) | ((unsigned)f2bf(o8[2 * i + 1]) << 16);
    *(u32x4*)(ldsh + VF_OFF / 2 + row * 136 + sub * 8) = pk;
  }
  __syncthreads();

  // ---------------- FFN in two 16-row halves -------------------------------
  for (int p = 0; p < 2; ++p) {
    // FFN1: Hhalf = relu(O1[p] @ w1 + b1), via MFMA (wave w -> coltiles 4w..4w+3)
    {
      f32x4 acc[4];
      #pragma unroll
      for (int c = 0; c < 4; ++c) {
        const int col = (4 * w + c) * 16 + lr;
        const float b = b1[col];
        acc[c] = (f32x4){b, b, b, b};
      }
      #pragma unroll
      for (int kk = 0; kk < 4; ++kk) {
        const bf16x8 a = *(const bf16x8*)(ldsh + VF_OFF / 2 + (p * 16 + lr) * 136 + kk * 32 + lg * 8);
        #pragma unroll
        for (int c = 0; c < 4; ++c) {
          const int chunk = 96 + (4 * w + c) * 4 + kk;
          const bf16x8 b = *(const bf16x8*)(wpack + ((size_t)chunk * 64 + l) * 8);
          acc[c] = __builtin_amdgcn_mfma_f32_16x16x32_bf16(a, b, acc[c], 0, 0, 0);
        }
      }
      #pragma unroll
      for (int c = 0; c < 4; ++c) {
        const int col = (4 * w + c) * 16 + lr;
        #pragma unroll
        for (int e = 0; e < 4; ++e)
          ldsh[H_OFF / 2 + (lg * 4 + e) * 552 + col] = f2bf(fmaxf(acc[c][e], 0.0f));
      }
    }
    __syncthreads();

    // FFN2: O2half = Hhalf @ w2 + b2 + O1[p], via MFMA (wave w -> coltile w)
    {
      const int col = w * 16 + lr;
      const float b = b2[col];
      f32x4 acc = {b, b, b, b};
      #pragma unroll
      for (int kk = 0; kk < 16; ++kk) {
        const bf16x8 a = *(const bf16x8*)(ldsh + H_OFF / 2 + lr * 552 + kk * 32 + lg * 8);
        const int chunk = 224 + w * 16 + kk;
        const bf16x8 bb = *(const bf16x8*)(wpack + ((size_t)chunk * 64 + l) * 8);
        acc = __builtin_amdgcn_mfma_f32_16x16x32_bf16(a, bb, acc, 0, 0, 0);
      }
      #pragma unroll
      for (int e = 0; e < 4; ++e) {
        const int rl = lg * 4 + e;
        const int srow = p * 16 + rl;
        const float res = ldsf[KF_OFF / 4 + srow * 132 + col];
        ldsf[O2_OFF / 4 + rl * 132 + col] = acc[e] + res;
      }
    }
    __syncthreads();

    // LN2 + transposed store (row r16, 32 threads x 4 cols)
    {
      const int r16 = t >> 5, sub = t & 31;
      const float4 v = *(const float4*)(ldsf + O2_OFF / 4 + r16 * 132 + sub * 4);
      float sum = v.x + v.y + v.z + v.w;
      #pragma unroll
      for (int m = 1; m < 32; m <<= 1) sum += __shfl_xor(sum, m);
      const float mu = sum * (1.0f / 128.0f);
      float s2 = 0.0f;
      s2 += (v.x - mu) * (v.x - mu); s2 += (v.y - mu) * (v.y - mu);
      s2 += (v.z - mu) * (v.z - mu); s2 += (v.w - mu) * (v.w - mu);
      #pragma unroll
      for (int m = 1; m < 32; m <<= 1) s2 += __shfl_xor(s2, m);
      const float rstd = rsqrtf(s2 * (1.0f / 128.0f) + 1e-5f);
      const int c0 = sub * 4;
      float4 r;
      r.x = (v.x - mu) * rstd * ln2g[c0 + 0] + ln2b[c0 + 0];
      r.y = (v.y - mu) * rstd * ln2g[c0 + 1] + ln2b[c0 + 1];
      r.z = (v.z - mu) * rstd * ln2g[c0 + 2] + ln2b[c0 + 2];
      r.w = (v.w - mu) * rstd * ln2g[c0 + 3] + ln2b[c0 + 3];
      const int s = p * 16 + r16;
      *(float4*)(out + ((size_t)s * NN + n) * CC + c0) = r;
    }
    __syncthreads();
  }
}

// ---------------------------------------------------------------------------
// Fallback: round-1 fp32 kernel (passed, 3332 us) if ws too small for packing.
// ---------------------------------------------------------------------------
__global__ __launch_bounds__(512, 4) void fused_retention_block(
    const float* __restrict__ x,
    const float* __restrict__ wq, const float* __restrict__ bq,
    const float* __restrict__ wk, const float* __restrict__ bk,
    const float* __restrict__ wv, const float* __restrict__ bv,
    const float* __restrict__ ln1g, const float* __restrict__ ln1b,
    const float* __restrict__ w1, const float* __restrict__ b1,
    const float* __restrict__ w2, const float* __restrict__ b2,
    const float* __restrict__ ln2g, const float* __restrict__ ln2b,
    float* __restrict__ out)
{
  const int n = blockIdx.x;
  const int t = threadIdx.x;
  __shared__ float SM[3 * BS * QS];
  float* Qs = SM;
  float* Ks = SM + BS * QS;
  float* Vs = SM + 2 * BS * QS;
  {
    const int o4 = t & 31;
    const int sp = t >> 5;
    const float* xr0 = x + ((size_t)(2 * sp) * NN + n) * CC;
    const float* xr1 = xr0 + (size_t)NN * CC;
    for (int m = 0; m < 3; ++m) {
      const float* W  = (m == 0) ? wq : (m == 1) ? wk : wv;
      const float* bb = (m == 0) ? bq : (m == 1) ? bk : bv;
      float* O = SM + m * BS * QS;
      float b4[4];
      *(float4*)b4 = *(const float4*)(bb + o4 * 4);
      float a0[4] = {b4[0], b4[1], b4[2], b4[3]};
      float a1[4] = {b4[0], b4[1], b4[2], b4[3]};
      for (int c4 = 0; c4 < 32; ++c4) {
        float xa4[4], xb4[4];
        *(float4*)xa4 = *(const float4*)(xr0 + c4 * 4);
        *(float4*)xb4 = *(const float4*)(xr1 + c4 * 4);
        const float* wp = W + (c4 * 4) * CC + o4 * 4;
        #pragma unroll
        for (int j = 0; j < 4; ++j) {
          float w4[4];
          *(float4*)w4 = *(const float4*)(wp + j * CC);
          #pragma unroll
          for (int e = 0; e < 4; ++e) { a0[e] += xa4[j] * w4[e]; a1[e] += xb4[j] * w4[e]; }
        }
      }
      float* q0 = O + (2 * sp) * QS + o4 * 4;
      float* q1 = O + (2 * sp + 1) * QS + o4 * 4;
      #pragma unroll
      for (int e = 0; e < 4; ++e) { q0[e] = a0[e]; q1[e] = a1[e]; }
    }
  }
  __syncthreads();
  {
    const int tt = t & 255;
    const int s = tt >> 3;
    const int h = tt & 7;
    float* row = ((t < 256) ? Qs : Ks) + s * QS + h * DD;
    float v[DD];
    #pragma unroll
    for (int d = 0; d < DD; ++d) v[d] = row[d];
    #pragma unroll
    for (int d = 0; d < DD; ++d) {
      const int j = d >> 1;
      const float a = exp2f(-1.89824462565f * (float)j);
      const float ang = (float)s * a;
      const float sn = sinf(ang);
      const float cs = cosf(ang);
      const float rot = (d < 8) ? -v[2 * d + 1] : v[2 * (d - 8)];
      row[d] = v[d] * cs + rot * sn;
    }
  }
  __syncthreads();
  if (t < 256) {
    const int h = t >> 5;
    const int qi = t & 31;
    const float dec = log1pf(-exp2f(-(1.0f + 0.375f * (float)h)));
    float q[DD];
    const float* Qr = Qs + qi * QS + h * DD;
    #pragma unroll
    for (int d = 0; d < DD; ++d) q[d] = Qr[d];
    float sc[BS];
    float mx = -3.0e38f;
    #pragma unroll
    for (int jj = 0; jj < BS; ++jj) {
      const float* Kr = Ks + jj * QS + h * DD;
      float acc = fabsf((float)(qi - jj)) * dec;
      #pragma unroll
      for (int d = 0; d < DD; ++d) acc += q[d] * Kr[d];
      sc[jj] = acc;
      mx = fmaxf(mx, acc);
    }
    float sum = 0.0f;
    #pragma unroll
    for (int jj = 0; jj < BS; ++jj) { const float p = __expf(sc[jj] - mx); sc[jj] = p; sum += p; }
    const float inv = 1.0f / sum;
    float o[DD];
    #pragma unroll
    for (int d = 0; d < DD; ++d) o[d] = 0.0f;
    #pragma unroll
    for (int jj = 0; jj < BS; ++jj) {
      const float p = sc[jj] * inv;
      const float* Vr = Vs + jj * QS + h * DD;
      #pragma unroll
      for (int d = 0; d < DD; ++d) o[d] += p * Vr[d];
    }
    float* Od = Qs + qi * QS + h * DD;
    #pragma unroll
    for (int d = 0; d < DD; ++d) Od[d] = o[d];
  }
  __syncthreads();
  {
    const int row = t >> 4;
    const int sub = t & 15;
    float* Orow = Qs + row * QS + sub * 8;
    const float* xrow = x + ((size_t)row * NN + n) * CC + sub * 8;
    float v[8];
    #pragma unroll
    for (int i = 0; i < 8; ++i) v[i] = Orow[i] + xrow[i];
    float sum = 0.0f;
    #pragma unroll
    for (int i = 0; i < 8; ++i) sum += v[i];
    #pragma unroll
    for (int m = 1; m < 16; m <<= 1) sum += __shfl_xor(sum, m);
    const float mu = sum * (1.0f / 128.0f);
    float s2 = 0.0f;
    #pragma unroll
    for (int i = 0; i < 8; ++i) { const float d = v[i] - mu; s2 += d * d; }
    #pragma unroll
    for (int m = 1; m < 16; m <<= 1) s2 += __shfl_xor(s2, m);
    const float rstd = rsqrtf(s2 * (1.0f / 128.0f) + 1e-5f);
    #pragma unroll
    for (int i = 0; i < 8; ++i) {
      const int c = sub * 8 + i;
      Orow[i] = (v[i] - mu) * rstd * ln1g[c] + ln1b[c];
    }
  }
  __syncthreads();
  float* Hb = Ks;
  const int f4  = t & 127;
  const int sb4 = (t >> 7) * 4;
  const int o4f = t & 31;
  const int sF  = t >> 5;
  for (int p = 0; p < 2; ++p) {
    {
      float acc[4][4];
      float b14[4];
      *(float4*)b14 = *(const float4*)(b1 + f4 * 4);
      #pragma unroll
      for (int i = 0; i < 4; ++i)
        #pragma unroll
        for (int e = 0; e < 4; ++e) acc[i][e] = b14[e];
      const float* O1b = Qs + (p * 16 + sb4) * QS;
      for (int c = 0; c < CC; ++c) {
        float w4[4];
        *(float4*)w4 = *(const float4*)(w1 + c * FF + f4 * 4);
        #pragma unroll
        for (int i = 0; i < 4; ++i) {
          const float xv = O1b[i * QS + c];
          #pragma unroll
          for (int e = 0; e < 4; ++e) acc[i][e] += xv * w4[e];
        }
      }
      #pragma unroll
      for (int i = 0; i < 4; ++i) {
        float4 r;
        r.x = fmaxf(acc[i][0], 0.0f); r.y = fmaxf(acc[i][1], 0.0f);
        r.z = fmaxf(acc[i][2], 0.0f); r.w = fmaxf(acc[i][3], 0.0f);
        *(float4*)(Hb + (sb4 + i) * FF + f4 * 4) = r;
      }
    }
    __syncthreads();
    {
      const int s = p * 16 + sF;
      float acc[4];
      *(float4*)acc = *(const float4*)(b2 + o4f * 4);
      const float* hrow = Hb + sF * FF;
      for (int k = 0; k < FF; ++k) {
        const float hv = hrow[k];
        float w4[4];
        *(float4*)w4 = *(const float4*)(w2 + k * CC + o4f * 4);
        #pragma unroll
        for (int e = 0; e < 4; ++e) acc[e] += hv * w4[e];
      }
      const float* res = Qs + s * QS + o4f * 4;
      #pragma unroll
      for (int e = 0; e < 4; ++e) acc[e] += res[e];
      float sum = acc[0] + acc[1] + acc[2] + acc[3];
      #pragma unroll
      for (int m = 1; m < 32; m <<= 1) sum += __shfl_xor(sum, m);
      const float mu = sum * (1.0f / 128.0f);
      float s2 = 0.0f;
      #pragma unroll
      for (int e = 0; e < 4; ++e) { const float d = acc[e] - mu; s2 += d * d; }
      #pragma unroll
      for (int m = 1; m < 32; m <<= 1) s2 += __shfl_xor(s2, m);
      const float rstd = rsqrtf(s2 * (1.0f / 128.0f) + 1e-5f);
      float4 r;
      const int c0 = o4f * 4;
      r.x = (acc[0] - mu) * rstd * ln2g[c0 + 0] + ln2b[c0 + 0];
      r.y = (acc[1] - mu) * rstd * ln2g[c0 + 1] + ln2b[c0 + 1];
      r.z = (acc[2] - mu) * rstd * ln2g[c0 + 2] + ln2b[c0 + 2];
      r.w = (acc[3] - mu) * rstd * ln2g[c0 + 3] + ln2b[c0 + 3];
      *(float4*)(out + ((size_t)s * NN + n) * CC + c0) = r;
    }
    __syncthreads();
  }
}

extern "C" void kernel_launch(void* const* d_in, const int* in_sizes, int n_in,
                              void* d_out, int out_size, void* d_ws, size_t ws_size,
                              hipStream_t stream) {
  (void)in_sizes; (void)n_in; (void)out_size;
  const float* x    = (const float*)d_in[0];
  const float* wq   = (const float*)d_in[1];
  const float* bq_  = (const float*)d_in[2];
  const float* wk   = (const float*)d_in[3];
  const float* bk_  = (const float*)d_in[4];
  const float* wv   = (const float*)d_in[5];
  const float* bv_  = (const float*)d_in[6];
  const float* ln1g = (const float*)d_in[7];
  const float* ln1b = (const float*)d_in[8];
  const float* w1   = (const float*)d_in[9];
  const float* b1   = (const float*)d_in[10];
  const float* w2   = (const float*)d_in[11];
  const float* b2   = (const float*)d_in[12];
  const float* ln2g = (const float*)d_in[13];
  const float* ln2b = (const float*)d_in[14];
  float* outp = (float*)d_out;

  if (ws_size >= (size_t)22528 * 16) {
    unsigned short* wpack = (unsigned short*)d_ws;
    pack_weights<<<88, 256, 0, stream>>>(wq, wk, wv, w1, w2, wpack);
    fused_mfma<<<NN, 512, LDS_BYTES, stream>>>(
        x, bq_, bk_, bv_, ln1g, ln1b, b1, b2, ln2g, ln2b, wpack, outp);
  } else {
    fused_retention_block<<<NN, 512, 0, stream>>>(
        x, wq, bq_, wk, bk_, wv, bv_, ln1g, ln1b,
        w1, b1, w2, b2, ln2g, ln2b, outp);
  }
}

// Round 3
// 600.324 us; speedup vs baseline: 5.5501x; 1.0525x over previous
//
#include <hip/hip_runtime.h>

// Fused retention block, MFMA + table-rotary + pair-split attention.
// grid = 8192 (one block per location n), 512 threads = 8 waves.
// LDS pool (bytes):
//   [0,8704)       XB bf16[32][136]  x tile (residual)      | FFN: H bf16[16][552] = [0,17664)
//   [8704,17408)   QB bf16[32][136]  Q (rotated) -> attn-out
//   [17408,26112)  KB bf16[32][136]  K (rotated)
//   [26112,43008)  VF f32[32][132]   V                      | FFN: O1B bf16[32][136] @26112, O2F f32[16][132] @34816
//   [43008,45184)  SIN f32[32][17]   (dead after QKV epilogue)
//   [45184,47360)  COS f32[32][17]
// Pool 47360 B -> 3 blocks/CU by LDS; __launch_bounds__(512,6) caps VGPR at 85.

#define NN 8192
#define BS 32
#define CC 128
#define HH 8
#define DD 16
#define FF 512
#define QS 129   // fp32 fallback stride

typedef __attribute__((ext_vector_type(8))) short bf16x8;
typedef __attribute__((ext_vector_type(4))) float f32x4;
typedef __attribute__((ext_vector_type(4))) unsigned int u32x4;

#define XB_H 0
#define QB_H 4352
#define KB_H 8704
#define VF_F 6528
#define O1B_H 13056
#define O2F_F 8704
#define H_H 0
#define SIN_F 10752
#define COS_F 11296
#define LDS_BYTES 47360

__device__ inline unsigned short f2bf(float f) {
  unsigned u = __builtin_bit_cast(unsigned, f);
  u = (u + 0x7FFFu + ((u >> 16) & 1u)) >> 16;
  return (unsigned short)u;
}
__device__ inline float bf2f(unsigned short h) {
  unsigned u = ((unsigned)h) << 16;
  return __builtin_bit_cast(float, u);
}

// ---------------------------------------------------------------------------
// Pack kernel (unchanged from r2): weights -> bf16 MFMA B-fragments.
// ---------------------------------------------------------------------------
__global__ void pack_weights(const float* __restrict__ wq, const float* __restrict__ wk,
                             const float* __restrict__ wv, const float* __restrict__ w1,
                             const float* __restrict__ w2, unsigned short* __restrict__ outp)
{
  const int id = blockIdx.x * 256 + threadIdx.x;
  if (id >= 22528) return;
  const int l = id & 63;
  const int chunk = id >> 6;
  const float* W; int ldw, colbase, k0;
  if (chunk < 96) {
    const int ct = chunk >> 2, kk = chunk & 3;
    W = (ct < 8) ? wq : (ct < 16) ? wk : wv;
    ldw = CC; colbase = (ct & 7) * 16 + (l & 15); k0 = kk * 32 + (l >> 4) * 8;
  } else if (chunk < 224) {
    const int c2 = chunk - 96, ct = c2 >> 2, kk = c2 & 3;
    W = w1; ldw = FF; colbase = ct * 16 + (l & 15); k0 = kk * 32 + (l >> 4) * 8;
  } else {
    const int c2 = chunk - 224, ct = c2 >> 4, kk = c2 & 15;
    W = w2; ldw = CC; colbase = ct * 16 + (l & 15); k0 = kk * 32 + (l >> 4) * 8;
  }
  unsigned int o[4];
  #pragma unroll
  for (int jj = 0; jj < 4; ++jj) {
    const unsigned lo = f2bf(W[(size_t)(k0 + 2 * jj) * ldw + colbase]);
    const unsigned hi = f2bf(W[(size_t)(k0 + 2 * jj + 1) * ldw + colbase]);
    o[jj] = lo | (hi << 16);
  }
  *(u32x4*)(outp + (size_t)id * 8) = (u32x4){o[0], o[1], o[2], o[3]};
}

__global__ __launch_bounds__(512, 6) void fused_mfma(
    const float* __restrict__ x,
    const float* __restrict__ bq, const float* __restrict__ bk, const float* __restrict__ bv,
    const float* __restrict__ ln1g, const float* __restrict__ ln1b,
    const float* __restrict__ b1, const float* __restrict__ b2,
    const float* __restrict__ ln2g, const float* __restrict__ ln2b,
    const unsigned short* __restrict__ wpack,
    float* __restrict__ out)
{
  extern __shared__ char smem[];
  float* ldsf = (float*)smem;
  unsigned short* ldsh = (unsigned short*)smem;
  const int n = blockIdx.x;
  const int t = threadIdx.x;
  const int w = t >> 6;
  const int l = t & 63;
  const int lr = l & 15;
  const int lg = l >> 4;

  // ---------------- stage X -> bf16 LDS + rotary sin/cos table -------------
  {
    const int s = t >> 4, c0 = (t & 15) * 8;
    const float* xp = x + ((size_t)s * NN + n) * CC + c0;
    const float4 v0 = *(const float4*)xp;
    const float4 v1 = *(const float4*)(xp + 4);
    u32x4 pk;
    pk[0] = (unsigned)f2bf(v0.x) | ((unsigned)f2bf(v0.y) << 16);
    pk[1] = (unsigned)f2bf(v0.z) | ((unsigned)f2bf(v0.w) << 16);
    pk[2] = (unsigned)f2bf(v1.x) | ((unsigned)f2bf(v1.y) << 16);
    pk[3] = (unsigned)f2bf(v1.z) | ((unsigned)f2bf(v1.w) << 16);
    *(u32x4*)(ldsh + XB_H + s * 136 + c0) = pk;
    // table entry: s' = t>>4, d = t&15
    const int d = t & 15;
    const float a = exp2f(-1.89824462565f * (float)(d >> 1));
    const float ang = (float)s * a;
    ldsf[SIN_F + s * 17 + d] = sinf(ang);
    ldsf[COS_F + s * 17 + d] = cosf(ang);
  }
  __syncthreads();

  // ---------------- QKV MFMA + fused rotary epilogue -----------------------
  {
    f32x4 acc[2][3];
    #pragma unroll
    for (int c = 0; c < 3; ++c) {
      const int ct = 3 * w + c;
      const int col = (ct & 7) * 16 + lr;
      const float* bb = (ct < 8) ? bq : (ct < 16) ? bk : bv;
      const float b = bb[col];
      acc[0][c] = (f32x4){b, b, b, b};
      acc[1][c] = acc[0][c];
    }
    #pragma unroll
    for (int kk = 0; kk < 4; ++kk) {
      const bf16x8 a0 = *(const bf16x8*)(ldsh + XB_H + lr * 136 + kk * 32 + lg * 8);
      const bf16x8 a1 = *(const bf16x8*)(ldsh + XB_H + (16 + lr) * 136 + kk * 32 + lg * 8);
      #pragma unroll
      for (int c = 0; c < 3; ++c) {
        const int ct = 3 * w + c;
        const bf16x8 b = *(const bf16x8*)(wpack + ((size_t)(ct * 4 + kk) * 64 + l) * 8);
        acc[0][c] = __builtin_amdgcn_mfma_f32_16x16x32_bf16(a0, b, acc[0][c], 0, 0, 0);
        acc[1][c] = __builtin_amdgcn_mfma_f32_16x16x32_bf16(a1, b, acc[1][c], 0, 0, 0);
      }
    }
    // rotary constants for this lane (col d = lr)
    float sn[2][4], cs[2][4];
    if (3 * w < 16) {   // wave-uniform: only waves holding Q/K coltiles
      #pragma unroll
      for (int rt = 0; rt < 2; ++rt)
        #pragma unroll
        for (int e = 0; e < 4; ++e) {
          const int row = rt * 16 + lg * 4 + e;
          sn[rt][e] = ldsf[SIN_F + row * 17 + lr];
          cs[rt][e] = ldsf[COS_F + row * 17 + lr];
        }
    }
    const int pd = (lr < 8) ? (2 * lr + 1) : (2 * lr - 16);
    const float sgn = (lr < 8) ? -1.0f : 1.0f;
    const int psrc = (l & 48) | pd;
    #pragma unroll
    for (int c = 0; c < 3; ++c) {
      const int ct = 3 * w + c;
      if (ct < 16) {
        const int dst = (ct < 8) ? QB_H : KB_H;
        const int colbase = (ct & 7) * 16;
        #pragma unroll
        for (int rt = 0; rt < 2; ++rt)
          #pragma unroll
          for (int e = 0; e < 4; ++e) {
            const float v = acc[rt][c][e];
            const float pv = __shfl(v, psrc);
            const float r = v * cs[rt][e] + sgn * pv * sn[rt][e];
            ldsh[dst + (rt * 16 + lg * 4 + e) * 136 + colbase + lr] = f2bf(r);
          }
      } else {
        const int col = (ct & 7) * 16 + lr;
        #pragma unroll
        for (int rt = 0; rt < 2; ++rt)
          #pragma unroll
          for (int e = 0; e < 4; ++e)
            ldsf[VF_F + (rt * 16 + lg * 4 + e) * 132 + col] = acc[rt][c][e];
      }
    }
  }
  __syncthreads();

  // ---------------- attention: all 512 threads, lane-pair jj split ---------
  {
    const int pair = t >> 1, jh = t & 1;
    const int h = pair >> 5;              // == wave id
    const int qi = pair & 31;
    const int j0 = jh * 16;
    const float dec = log1pf(-exp2f(-(1.0f + 0.375f * (float)h)));
    float q[DD];
    const unsigned short* Qr = ldsh + QB_H + qi * 136 + h * DD;
    #pragma unroll
    for (int d = 0; d < DD; ++d) q[d] = bf2f(Qr[d]);
    float sc[16];
    float mx = -3.0e38f;
    #pragma unroll
    for (int i = 0; i < 16; ++i) {
      const int jj = j0 + i;
      const unsigned short* Kr = ldsh + KB_H + jj * 136 + h * DD;
      float a = fabsf((float)(qi - jj)) * dec;
      #pragma unroll
      for (int d = 0; d < DD; ++d) a += q[d] * bf2f(Kr[d]);
      sc[i] = a;
      mx = fmaxf(mx, a);
    }
    mx = fmaxf(mx, __shfl_xor(mx, 1));
    float sum = 0.0f;
    float o[DD];
    #pragma unroll
    for (int d = 0; d < DD; ++d) o[d] = 0.0f;
    #pragma unroll
    for (int i = 0; i < 16; ++i) {
      const float p = __expf(sc[i] - mx);
      sum += p;
      const float* Vr = ldsf + VF_F + (j0 + i) * 132 + h * DD;
      #pragma unroll
      for (int d = 0; d < DD; ++d) o[d] += p * Vr[d];
    }
    sum += __shfl_xor(sum, 1);
    const float inv = 1.0f / sum;
    #pragma unroll
    for (int d = 0; d < DD; ++d) o[d] = (o[d] + __shfl_xor(o[d], 1)) * inv;
    // write my 8-element half of the O row (bf16, over Q)
    const int d0 = jh * 8;
    u32x4 pk;
    #pragma unroll
    for (int i = 0; i < 4; ++i)
      pk[i] = (unsigned)f2bf(o[d0 + 2 * i]) | ((unsigned)f2bf(o[d0 + 2 * i + 1]) << 16);
    *(u32x4*)(ldsh + QB_H + qi * 136 + h * DD + d0) = pk;
  }
  __syncthreads();

  // ---------------- LN1(attn_out + x) -> O1 bf16 @ O1B ---------------------
  {
    const int row = t >> 4, sub = t & 15;
    const unsigned short* Or = ldsh + QB_H + row * 136 + sub * 8;
    const unsigned short* Xr = ldsh + XB_H + row * 136 + sub * 8;
    float v[8];
    #pragma unroll
    for (int i = 0; i < 8; ++i) v[i] = bf2f(Or[i]) + bf2f(Xr[i]);
    float sum = 0.0f;
    #pragma unroll
    for (int i = 0; i < 8; ++i) sum += v[i];
    #pragma unroll
    for (int m = 1; m < 16; m <<= 1) sum += __shfl_xor(sum, m);
    const float mu = sum * (1.0f / 128.0f);
    float s2 = 0.0f;
    #pragma unroll
    for (int i = 0; i < 8; ++i) { const float d = v[i] - mu; s2 += d * d; }
    #pragma unroll
    for (int m = 1; m < 16; m <<= 1) s2 += __shfl_xor(s2, m);
    const float rstd = rsqrtf(s2 * (1.0f / 128.0f) + 1e-5f);
    u32x4 pk;
    #pragma unroll
    for (int i = 0; i < 4; ++i) {
      const int c = sub * 8 + 2 * i;
      const float e0 = (v[2 * i] - mu) * rstd * ln1g[c] + ln1b[c];
      const float e1 = (v[2 * i + 1] - mu) * rstd * ln1g[c + 1] + ln1b[c + 1];
      pk[i] = (unsigned)f2bf(e0) | ((unsigned)f2bf(e1) << 16);
    }
    *(u32x4*)(ldsh + O1B_H + row * 136 + sub * 8) = pk;
  }
  __syncthreads();

  // ---------------- FFN in two 16-row halves -------------------------------
  for (int p = 0; p < 2; ++p) {
    // FFN1: H = relu(O1[p] @ w1 + b1)
    {
      f32x4 acc[4];
      #pragma unroll
      for (int c = 0; c < 4; ++c) {
        const float b = b1[(4 * w + c) * 16 + lr];
        acc[c] = (f32x4){b, b, b, b};
      }
      #pragma unroll
      for (int kk = 0; kk < 4; ++kk) {
        const bf16x8 a = *(const bf16x8*)(ldsh + O1B_H + (p * 16 + lr) * 136 + kk * 32 + lg * 8);
        #pragma unroll
        for (int c = 0; c < 4; ++c) {
          const int chunk = 96 + (4 * w + c) * 4 + kk;
          const bf16x8 b = *(const bf16x8*)(wpack + ((size_t)chunk * 64 + l) * 8);
          acc[c] = __builtin_amdgcn_mfma_f32_16x16x32_bf16(a, b, acc[c], 0, 0, 0);
        }
      }
      #pragma unroll
      for (int c = 0; c < 4; ++c) {
        const int col = (4 * w + c) * 16 + lr;
        #pragma unroll
        for (int e = 0; e < 4; ++e)
          ldsh[H_H + (lg * 4 + e) * 552 + col] = f2bf(fmaxf(acc[c][e], 0.0f));
      }
    }
    __syncthreads();

    // FFN2: O2 = H @ w2 + b2 + O1[p]
    {
      const int col = w * 16 + lr;
      const float b = b2[col];
      f32x4 acc = {b, b, b, b};
      #pragma unroll
      for (int kk = 0; kk < 16; ++kk) {
        const bf16x8 a = *(const bf16x8*)(ldsh + H_H + lr * 552 + kk * 32 + lg * 8);
        const int chunk = 224 + w * 16 + kk;
        const bf16x8 bb = *(const bf16x8*)(wpack + ((size_t)chunk * 64 + l) * 8);
        acc = __builtin_amdgcn_mfma_f32_16x16x32_bf16(a, bb, acc, 0, 0, 0);
      }
      #pragma unroll
      for (int e = 0; e < 4; ++e) {
        const int rl = lg * 4 + e;
        const float res = bf2f(ldsh[O1B_H + (p * 16 + rl) * 136 + col]);
        ldsf[O2F_F + rl * 132 + col] = acc[e] + res;
      }
    }
    __syncthreads();

    // LN2 + transposed store
    {
      const int r16 = t >> 5, sub = t & 31;
      const float4 v = *(const float4*)(ldsf + O2F_F + r16 * 132 + sub * 4);
      float sum = v.x + v.y + v.z + v.w;
      #pragma unroll
      for (int m = 1; m < 32; m <<= 1) sum += __shfl_xor(sum, m);
      const float mu = sum * (1.0f / 128.0f);
      float s2 = 0.0f;
      s2 += (v.x - mu) * (v.x - mu); s2 += (v.y - mu) * (v.y - mu);
      s2 += (v.z - mu) * (v.z - mu); s2 += (v.w - mu) * (v.w - mu);
      #pragma unroll
      for (int m = 1; m < 32; m <<= 1) s2 += __shfl_xor(s2, m);
      const float rstd = rsqrtf(s2 * (1.0f / 128.0f) + 1e-5f);
      const int c0 = sub * 4;
      float4 r;
      r.x = (v.x - mu) * rstd * ln2g[c0 + 0] + ln2b[c0 + 0];
      r.y = (v.y - mu) * rstd * ln2g[c0 + 1] + ln2b[c0 + 1];
      r.z = (v.z - mu) * rstd * ln2g[c0 + 2] + ln2b[c0 + 2];
      r.w = (v.w - mu) * rstd * ln2g[c0 + 3] + ln2b[c0 + 3];
      const int s = p * 16 + r16;
      *(float4*)(out + ((size_t)s * NN + n) * CC + c0) = r;
    }
    __syncthreads();
  }
}

// ---------------------------------------------------------------------------
// Fallback: round-1 fp32 kernel (passed, 3332 us) if ws too small for packing.
// ---------------------------------------------------------------------------
__global__ __launch_bounds__(512, 4) void fused_retention_block(
    const float* __restrict__ x,
    const float* __restrict__ wq, const float* __restrict__ bq,
    const float* __restrict__ wk, const float* __restrict__ bk,
    const float* __restrict__ wv, const float* __restrict__ bv,
    const float* __restrict__ ln1g, const float* __restrict__ ln1b,
    const float* __restrict__ w1, const float* __restrict__ b1,
    const float* __restrict__ w2, const float* __restrict__ b2,
    const float* __restrict__ ln2g, const float* __restrict__ ln2b,
    float* __restrict__ out)
{
  const int n = blockIdx.x;
  const int t = threadIdx.x;
  __shared__ float SM[3 * BS * QS];
  float* Qs = SM;
  float* Ks = SM + BS * QS;
  float* Vs = SM + 2 * BS * QS;
  {
    const int o4 = t & 31;
    const int sp = t >> 5;
    const float* xr0 = x + ((size_t)(2 * sp) * NN + n) * CC;
    const float* xr1 = xr0 + (size_t)NN * CC;
    for (int m = 0; m < 3; ++m) {
      const float* W  = (m == 0) ? wq : (m == 1) ? wk : wv;
      const float* bb = (m == 0) ? bq : (m == 1) ? bk : bv;
      float* O = SM + m * BS * QS;
      float b4[4];
      *(float4*)b4 = *(const float4*)(bb + o4 * 4);
      float a0[4] = {b4[0], b4[1], b4[2], b4[3]};
      float a1[4] = {b4[0], b4[1], b4[2], b4[3]};
      for (int c4 = 0; c4 < 32; ++c4) {
        float xa4[4], xb4[4];
        *(float4*)xa4 = *(const float4*)(xr0 + c4 * 4);
        *(float4*)xb4 = *(const float4*)(xr1 + c4 * 4);
        const float* wp = W + (c4 * 4) * CC + o4 * 4;
        #pragma unroll
        for (int j = 0; j < 4; ++j) {
          float w4[4];
          *(float4*)w4 = *(const float4*)(wp + j * CC);
          #pragma unroll
          for (int e = 0; e < 4; ++e) { a0[e] += xa4[j] * w4[e]; a1[e] += xb4[j] * w4[e]; }
        }
      }
      float* q0 = O + (2 * sp) * QS + o4 * 4;
      float* q1 = O + (2 * sp + 1) * QS + o4 * 4;
      #pragma unroll
      for (int e = 0; e < 4; ++e) { q0[e] = a0[e]; q1[e] = a1[e]; }
    }
  }
  __syncthreads();
  {
    const int tt = t & 255;
    const int s = tt >> 3;
    const int h = tt & 7;
    float* row = ((t < 256) ? Qs : Ks) + s * QS + h * DD;
    float v[DD];
    #pragma unroll
    for (int d = 0; d < DD; ++d) v[d] = row[d];
    #pragma unroll
    for (int d = 0; d < DD; ++d) {
      const int j = d >> 1;
      const float a = exp2f(-1.89824462565f * (float)j);
      const float ang = (float)s * a;
      const float sn = sinf(ang);
      const float cs = cosf(ang);
      const float rot = (d < 8) ? -v[2 * d + 1] : v[2 * (d - 8)];
      row[d] = v[d] * cs + rot * sn;
    }
  }
  __syncthreads();
  if (t < 256) {
    const int h = t >> 5;
    const int qi = t & 31;
    const float dec = log1pf(-exp2f(-(1.0f + 0.375f * (float)h)));
    float q[DD];
    const float* Qr = Qs + qi * QS + h * DD;
    #pragma unroll
    for (int d = 0; d < DD; ++d) q[d] = Qr[d];
    float sc[BS];
    float mx = -3.0e38f;
    #pragma unroll
    for (int jj = 0; jj < BS; ++jj) {
      const float* Kr = Ks + jj * QS + h * DD;
      float acc = fabsf((float)(qi - jj)) * dec;
      #pragma unroll
      for (int d = 0; d < DD; ++d) acc += q[d] * Kr[d];
      sc[jj] = acc;
      mx = fmaxf(mx, acc);
    }
    float sum = 0.0f;
    #pragma unroll
    for (int jj = 0; jj < BS; ++jj) { const float p = __expf(sc[jj] - mx); sc[jj] = p; sum += p; }
    const float inv = 1.0f / sum;
    float o[DD];
    #pragma unroll
    for (int d = 0; d < DD; ++d) o[d] = 0.0f;
    #pragma unroll
    for (int jj = 0; jj < BS; ++jj) {
      const float p = sc[jj] * inv;
      const float* Vr = Vs + jj * QS + h * DD;
      #pragma unroll
      for (int d = 0; d < DD; ++d) o[d] += p * Vr[d];
    }
    float* Od = Qs + qi * QS + h * DD;
    #pragma unroll
    for (int d = 0; d < DD; ++d) Od[d] = o[d];
  }
  __syncthreads();
  {
    const int row = t >> 4;
    const int sub = t & 15;
    float* Orow = Qs + row * QS + sub * 8;
    const float* xrow = x + ((size_t)row * NN + n) * CC + sub * 8;
    float v[8];
    #pragma unroll
    for (int i = 0; i < 8; ++i) v[i] = Orow[i] + xrow[i];
    float sum = 0.0f;
    #pragma unroll
    for (int i = 0; i < 8; ++i) sum += v[i];
    #pragma unroll
    for (int m = 1; m < 16; m <<= 1) sum += __shfl_xor(sum, m);
    const float mu = sum * (1.0f / 128.0f);
    float s2 = 0.0f;
    #pragma unroll
    for (int i = 0; i < 8; ++i) { const float d = v[i] - mu; s2 += d * d; }
    #pragma unroll
    for (int m = 1; m < 16; m <<= 1) s2 += __shfl_xor(s2, m);
    const float rstd = rsqrtf(s2 * (1.0f / 128.0f) + 1e-5f);
    #pragma unroll
    for (int i = 0; i < 8; ++i) {
      const int c = sub * 8 + i;
      Orow[i] = (v[i] - mu) * rstd * ln1g[c] + ln1b[c];
    }
  }
  __syncthreads();
  float* Hb = Ks;
  const int f4  = t & 127;
  const int sb4 = (t >> 7) * 4;
  const int o4f = t & 31;
  const int sF  = t >> 5;
  for (int p = 0; p < 2; ++p) {
    {
      float acc[4][4];
      float b14[4];
      *(float4*)b14 = *(const float4*)(b1 + f4 * 4);
      #pragma unroll
      for (int i = 0; i < 4; ++i)
        #pragma unroll
        for (int e = 0; e < 4; ++e) acc[i][e] = b14[e];
      const float* O1b = Qs + (p * 16 + sb4) * QS;
      for (int c = 0; c < CC; ++c) {
        float w4[4];
        *(float4*)w4 = *(const float4*)(w1 + c * FF + f4 * 4);
        #pragma unroll
        for (int i = 0; i < 4; ++i) {
          const float xv = O1b[i * QS + c];
          #pragma unroll
          for (int e = 0; e < 4; ++e) acc[i][e] += xv * w4[e];
        }
      }
      #pragma unroll
      for (int i = 0; i < 4; ++i) {
        float4 r;
        r.x = fmaxf(acc[i][0], 0.0f); r.y = fmaxf(acc[i][1], 0.0f);
        r.z = fmaxf(acc[i][2], 0.0f); r.w = fmaxf(acc[i][3], 0.0f);
        *(float4*)(Hb + (sb4 + i) * FF + f4 * 4) = r;
      }
    }
    __syncthreads();
    {
      const int s = p * 16 + sF;
      float acc[4];
      *(float4*)acc = *(const float4*)(b2 + o4f * 4);
      const float* hrow = Hb + sF * FF;
      for (int k = 0; k < FF; ++k) {
        const float hv = hrow[k];
        float w4[4];
        *(float4*)w4 = *(const float4*)(w2 + k * CC + o4f * 4);
        #pragma unroll
        for (int e = 0; e < 4; ++e) acc[e] += hv * w4[e];
      }
      const float* res = Qs + s * QS + o4f * 4;
      #pragma unroll
      for (int e = 0; e < 4; ++e) acc[e] += res[e];
      float sum = acc[0] + acc[1] + acc[2] + acc[3];
      #pragma unroll
      for (int m = 1; m < 32; m <<= 1) sum += __shfl_xor(sum, m);
      const float mu = sum * (1.0f / 128.0f);
      float s2 = 0.0f;
      #pragma unroll
      for (int e = 0; e < 4; ++e) { const float d = acc[e] - mu; s2 += d * d; }
      #pragma unroll
      for (int m = 1; m < 32; m <<= 1) s2 += __shfl_xor(s2, m);
      const float rstd = rsqrtf(s2 * (1.0f / 128.0f) + 1e-5f);
      float4 r;
      const int c0 = o4f * 4;
      r.x = (acc[0] - mu) * rstd * ln2g[c0 + 0] + ln2b[c0 + 0];
      r.y = (acc[1] - mu) * rstd * ln2g[c0 + 1] + ln2b[c0 + 1];
      r.z = (acc[2] - mu) * rstd * ln2g[c0 + 2] + ln2b[c0 + 2];
      r.w = (acc[3] - mu) * rstd * ln2g[c0 + 3] + ln2b[c0 + 3];
      *(float4*)(out + ((size_t)s * NN + n) * CC + c0) = r;
    }
    __syncthreads();
  }
}

extern "C" void kernel_launch(void* const* d_in, const int* in_sizes, int n_in,
                              void* d_out, int out_size, void* d_ws, size_t ws_size,
                              hipStream_t stream) {
  (void)in_sizes; (void)n_in; (void)out_size;
  const float* x    = (const float*)d_in[0];
  const float* wq   = (const float*)d_in[1];
  const float* bq_  = (const float*)d_in[2];
  const float* wk   = (const float*)d_in[3];
  const float* bk_  = (const float*)d_in[4];
  const float* wv   = (const float*)d_in[5];
  const float* bv_  = (const float*)d_in[6];
  const float* ln1g = (const float*)d_in[7];
  const float* ln1b = (const float*)d_in[8];
  const float* w1   = (const float*)d_in[9];
  const float* b1   = (const float*)d_in[10];
  const float* w2   = (const float*)d_in[11];
  const float* b2   = (const float*)d_in[12];
  const float* ln2g = (const float*)d_in[13];
  const float* ln2b = (const float*)d_in[14];
  float* outp = (float*)d_out;

  if (ws_size >= (size_t)22528 * 16) {
    unsigned short* wpack = (unsigned short*)d_ws;
    pack_weights<<<88, 256, 0, stream>>>(wq, wk, wv, w1, w2, wpack);
    fused_mfma<<<NN, 512, LDS_BYTES, stream>>>(
        x, bq_, bk_, bv_, ln1g, ln1b, b1, b2, ln2g, ln2b, wpack, outp);
  } else {
    fused_retention_block<<<NN, 512, 0, stream>>>(
        x, wq, bq_, wk, bk_, wv, bv_, ln1g, ln1b,
        w1, b1, w2, b2, ln2g, ln2b, outp);
  }
}

// Round 4
// 261.813 us; speedup vs baseline: 12.7262x; 2.2930x over previous
//
#include <hip/hip_runtime.h>

// Fused retention block, full-MFMA edition (QKV + attention + FFN on matrix cores).
// grid = 8192 (one block per location n), 512 threads = 8 waves (wave w = head w in attn).
// LDS pool 53248 B (52 KB) -> 3 blocks/CU. Offsets (bytes):
//   XB  [0,8704)       bf16[32][136] x tile (residual)   | FFN: O2F f32[16][132] @ [0,8448)
//   QB  [8704,17408)   bf16[32][136] rotated Q -> attn-out O
//   KB  [17408,26112)  bf16[32][136] rotated K           | LN1 out O1B bf16[32][136]
//   VB  [26112,34816)  bf16[32][136] V                   | FFN: H bf16[16][552] @ [26112,43776)
//   P   [34816,53248)  bf16 per-head [32][36] tiles      | also SIN/COS f32[32][17] @ [34816,39168)
//     (tables dead after QKV epilogue; P written in attention; H overlays VB+P in FFN)

#define NN 8192
#define BS 32
#define CC 128
#define HH 8
#define DD 16
#define FF 512
#define QS 129   // fp32 fallback stride

typedef __attribute__((ext_vector_type(8))) short bf16x8;
typedef __attribute__((ext_vector_type(4))) float f32x4;
typedef __attribute__((ext_vector_type(4))) unsigned int u32x4;
typedef __attribute__((ext_vector_type(2))) unsigned int u32x2;

#define XB_H 0
#define QB_H 4352
#define KB_H 8704
#define VB_H 13056
#define P_H 17408
#define P_HEAD 1152
#define P_STR 36
#define O1B_H 8704
#define H_H 13056
#define O2F_F 0
#define SIN_F 8704
#define COS_F 9248
#define LDS_BYTES 53248

__device__ inline unsigned short f2bf(float f) {
  unsigned u = __builtin_bit_cast(unsigned, f);
  u = (u + 0x7FFFu + ((u >> 16) & 1u)) >> 16;
  return (unsigned short)u;
}
__device__ inline float bf2f(unsigned short h) {
  unsigned u = ((unsigned)h) << 16;
  return __builtin_bit_cast(float, u);
}

// ---------------------------------------------------------------------------
// Pack kernel (unchanged): weights -> bf16 MFMA B-fragments in d_ws.
// ---------------------------------------------------------------------------
__global__ void pack_weights(const float* __restrict__ wq, const float* __restrict__ wk,
                             const float* __restrict__ wv, const float* __restrict__ w1,
                             const float* __restrict__ w2, unsigned short* __restrict__ outp)
{
  const int id = blockIdx.x * 256 + threadIdx.x;
  if (id >= 22528) return;
  const int l = id & 63;
  const int chunk = id >> 6;
  const float* W; int ldw, colbase, k0;
  if (chunk < 96) {
    const int ct = chunk >> 2, kk = chunk & 3;
    W = (ct < 8) ? wq : (ct < 16) ? wk : wv;
    ldw = CC; colbase = (ct & 7) * 16 + (l & 15); k0 = kk * 32 + (l >> 4) * 8;
  } else if (chunk < 224) {
    const int c2 = chunk - 96, ct = c2 >> 2, kk = c2 & 3;
    W = w1; ldw = FF; colbase = ct * 16 + (l & 15); k0 = kk * 32 + (l >> 4) * 8;
  } else {
    const int c2 = chunk - 224, ct = c2 >> 4, kk = c2 & 15;
    W = w2; ldw = CC; colbase = ct * 16 + (l & 15); k0 = kk * 32 + (l >> 4) * 8;
  }
  unsigned int o[4];
  #pragma unroll
  for (int jj = 0; jj < 4; ++jj) {
    const unsigned lo = f2bf(W[(size_t)(k0 + 2 * jj) * ldw + colbase]);
    const unsigned hi = f2bf(W[(size_t)(k0 + 2 * jj + 1) * ldw + colbase]);
    o[jj] = lo | (hi << 16);
  }
  *(u32x4*)(outp + (size_t)id * 8) = (u32x4){o[0], o[1], o[2], o[3]};
}

__global__ __launch_bounds__(512, 6) void fused_mfma(
    const float* __restrict__ x,
    const float* __restrict__ bq, const float* __restrict__ bk, const float* __restrict__ bv,
    const float* __restrict__ ln1g, const float* __restrict__ ln1b,
    const float* __restrict__ b1, const float* __restrict__ b2,
    const float* __restrict__ ln2g, const float* __restrict__ ln2b,
    const unsigned short* __restrict__ wpack,
    float* __restrict__ out)
{
  extern __shared__ char smem[];
  float* ldsf = (float*)smem;
  unsigned short* ldsh = (unsigned short*)smem;
  const int n = blockIdx.x;
  const int t = threadIdx.x;
  const int w = t >> 6;
  const int l = t & 63;
  const int lr = l & 15;
  const int lg = l >> 4;

  // ---------------- stage X -> bf16 LDS + rotary sin/cos table -------------
  {
    const int s = t >> 4, c0 = (t & 15) * 8;
    const float* xp = x + ((size_t)s * NN + n) * CC + c0;
    const float4 v0 = *(const float4*)xp;
    const float4 v1 = *(const float4*)(xp + 4);
    u32x4 pk;
    pk[0] = (unsigned)f2bf(v0.x) | ((unsigned)f2bf(v0.y) << 16);
    pk[1] = (unsigned)f2bf(v0.z) | ((unsigned)f2bf(v0.w) << 16);
    pk[2] = (unsigned)f2bf(v1.x) | ((unsigned)f2bf(v1.y) << 16);
    pk[3] = (unsigned)f2bf(v1.z) | ((unsigned)f2bf(v1.w) << 16);
    *(u32x4*)(ldsh + XB_H + s * 136 + c0) = pk;
    const int d = t & 15;
    const float a = exp2f(-1.89824462565f * (float)(d >> 1));
    const float ang = (float)s * a;
    ldsf[SIN_F + s * 17 + d] = sinf(ang);
    ldsf[COS_F + s * 17 + d] = cosf(ang);
  }
  __syncthreads();

  // ---------------- QKV MFMA + fused rotary epilogue (Q,K,V all bf16) ------
  {
    f32x4 acc[2][3];
    #pragma unroll
    for (int c = 0; c < 3; ++c) {
      const int ct = 3 * w + c;
      const int col = (ct & 7) * 16 + lr;
      const float* bb = (ct < 8) ? bq : (ct < 16) ? bk : bv;
      const float b = bb[col];
      acc[0][c] = (f32x4){b, b, b, b};
      acc[1][c] = acc[0][c];
    }
    #pragma unroll
    for (int kk = 0; kk < 4; ++kk) {
      const bf16x8 a0 = *(const bf16x8*)(ldsh + XB_H + lr * 136 + kk * 32 + lg * 8);
      const bf16x8 a1 = *(const bf16x8*)(ldsh + XB_H + (16 + lr) * 136 + kk * 32 + lg * 8);
      #pragma unroll
      for (int c = 0; c < 3; ++c) {
        const int ct = 3 * w + c;
        const bf16x8 b = *(const bf16x8*)(wpack + ((size_t)(ct * 4 + kk) * 64 + l) * 8);
        acc[0][c] = __builtin_amdgcn_mfma_f32_16x16x32_bf16(a0, b, acc[0][c], 0, 0, 0);
        acc[1][c] = __builtin_amdgcn_mfma_f32_16x16x32_bf16(a1, b, acc[1][c], 0, 0, 0);
      }
    }
    float sn[2][4], cs[2][4];
    if (3 * w < 16) {   // wave-uniform: only waves holding Q/K coltiles
      #pragma unroll
      for (int rt = 0; rt < 2; ++rt)
        #pragma unroll
        for (int e = 0; e < 4; ++e) {
          const int row = rt * 16 + lg * 4 + e;
          sn[rt][e] = ldsf[SIN_F + row * 17 + lr];
          cs[rt][e] = ldsf[COS_F + row * 17 + lr];
        }
    }
    const int pd = (lr < 8) ? (2 * lr + 1) : (2 * lr - 16);
    const float sgn = (lr < 8) ? -1.0f : 1.0f;
    const int psrc = (l & 48) | pd;
    #pragma unroll
    for (int c = 0; c < 3; ++c) {
      const int ct = 3 * w + c;
      const int colbase = (ct & 7) * 16;
      if (ct < 16) {
        const int dst = (ct < 8) ? QB_H : KB_H;
        #pragma unroll
        for (int rt = 0; rt < 2; ++rt)
          #pragma unroll
          for (int e = 0; e < 4; ++e) {
            const float v = acc[rt][c][e];
            const float pv = __shfl(v, psrc);
            const float r = v * cs[rt][e] + sgn * pv * sn[rt][e];
            ldsh[dst + (rt * 16 + lg * 4 + e) * 136 + colbase + lr] = f2bf(r);
          }
      } else {
        #pragma unroll
        for (int rt = 0; rt < 2; ++rt)
          #pragma unroll
          for (int e = 0; e < 4; ++e)
            ldsh[VB_H + (rt * 16 + lg * 4 + e) * 136 + colbase + lr] = f2bf(acc[rt][c][e]);
      }
    }
  }
  __syncthreads();

  // ---------------- MFMA attention: wave w = head w, no internal barriers --
  {
    const int h16 = w * 16;
    const float dec = log1pf(-exp2f(-(1.0f + 0.375f * (float)w)));
    const bf16x8 z = {};
    // S^T = K @ Q^T (D=16 padded to K=32; lg>=2 lanes carry zeros)
    bf16x8 Ak[2], Bq[2];
    #pragma unroll
    for (int kt = 0; kt < 2; ++kt)
      Ak[kt] = (lg < 2) ? *(const bf16x8*)(ldsh + KB_H + (kt * 16 + lr) * 136 + h16 + lg * 8) : z;
    #pragma unroll
    for (int qt = 0; qt < 2; ++qt)
      Bq[qt] = (lg < 2) ? *(const bf16x8*)(ldsh + QB_H + (qt * 16 + lr) * 136 + h16 + lg * 8) : z;
    f32x4 accs[2][2];
    #pragma unroll
    for (int kt = 0; kt < 2; ++kt)
      #pragma unroll
      for (int qt = 0; qt < 2; ++qt) {
        #pragma unroll
        for (int e = 0; e < 4; ++e) {
          const int q = qt * 16 + lr;
          const int k = kt * 16 + lg * 4 + e;
          accs[kt][qt][e] = fabsf((float)(q - k)) * dec;
        }
        accs[kt][qt] = __builtin_amdgcn_mfma_f32_16x16x32_bf16(Ak[kt], Bq[qt], accs[kt][qt], 0, 0, 0);
      }
    // softmax over k (rows): in-lane 8 + lanes {lr, lr+16, lr+32, lr+48}
    unsigned short* Pl = ldsh + P_H + w * P_HEAD;
    #pragma unroll
    for (int qt = 0; qt < 2; ++qt) {
      float mx = accs[0][qt][0];
      #pragma unroll
      for (int kt = 0; kt < 2; ++kt)
        #pragma unroll
        for (int e = 0; e < 4; ++e) mx = fmaxf(mx, accs[kt][qt][e]);
      mx = fmaxf(mx, __shfl_xor(mx, 16));
      mx = fmaxf(mx, __shfl_xor(mx, 32));
      float p[2][4];
      float sm = 0.0f;
      #pragma unroll
      for (int kt = 0; kt < 2; ++kt)
        #pragma unroll
        for (int e = 0; e < 4; ++e) { p[kt][e] = __expf(accs[kt][qt][e] - mx); sm += p[kt][e]; }
      sm += __shfl_xor(sm, 16);
      sm += __shfl_xor(sm, 32);
      const float inv = 1.0f / sm;
      #pragma unroll
      for (int kt = 0; kt < 2; ++kt) {
        u32x2 pw;
        pw[0] = (unsigned)f2bf(p[kt][0] * inv) | ((unsigned)f2bf(p[kt][1] * inv) << 16);
        pw[1] = (unsigned)f2bf(p[kt][2] * inv) | ((unsigned)f2bf(p[kt][3] * inv) << 16);
        *(u32x2*)(Pl + (qt * 16 + lr) * P_STR + kt * 16 + lg * 4) = pw;
      }
    }
    // PV: out = P @ V  (K=32 full)
    bf16x8 Bv;
    #pragma unroll
    for (int j = 0; j < 8; ++j)
      Bv[j] = (short)ldsh[VB_H + (lg * 8 + j) * 136 + h16 + lr];
    #pragma unroll
    for (int qt = 0; qt < 2; ++qt) {
      const bf16x8 Ap = *(const bf16x8*)(Pl + (qt * 16 + lr) * P_STR + lg * 8);
      f32x4 z4 = {0.0f, 0.0f, 0.0f, 0.0f};
      const f32x4 o = __builtin_amdgcn_mfma_f32_16x16x32_bf16(Ap, Bv, z4, 0, 0, 0);
      #pragma unroll
      for (int e = 0; e < 4; ++e)
        ldsh[QB_H + (qt * 16 + lg * 4 + e) * 136 + h16 + lr] = f2bf(o[e]);
    }
  }
  __syncthreads();

  // ---------------- LN1(attn_out + x) -> O1 bf16 @ KB region ---------------
  {
    const int row = t >> 4, sub = t & 15;
    const unsigned short* Or = ldsh + QB_H + row * 136 + sub * 8;
    const unsigned short* Xr = ldsh + XB_H + row * 136 + sub * 8;
    float v[8];
    #pragma unroll
    for (int i = 0; i < 8; ++i) v[i] = bf2f(Or[i]) + bf2f(Xr[i]);
    float sum = 0.0f;
    #pragma unroll
    for (int i = 0; i < 8; ++i) sum += v[i];
    #pragma unroll
    for (int m = 1; m < 16; m <<= 1) sum += __shfl_xor(sum, m);
    const float mu = sum * (1.0f / 128.0f);
    float s2 = 0.0f;
    #pragma unroll
    for (int i = 0; i < 8; ++i) { const float d = v[i] - mu; s2 += d * d; }
    #pragma unroll
    for (int m = 1; m < 16; m <<= 1) s2 += __shfl_xor(s2, m);
    const float rstd = rsqrtf(s2 * (1.0f / 128.0f) + 1e-5f);
    u32x4 pk;
    #pragma unroll
    for (int i = 0; i < 4; ++i) {
      const int c = sub * 8 + 2 * i;
      const float e0 = (v[2 * i] - mu) * rstd * ln1g[c] + ln1b[c];
      const float e1 = (v[2 * i + 1] - mu) * rstd * ln1g[c + 1] + ln1b[c + 1];
      pk[i] = (unsigned)f2bf(e0) | ((unsigned)f2bf(e1) << 16);
    }
    *(u32x4*)(ldsh + O1B_H + row * 136 + sub * 8) = pk;
  }
  __syncthreads();

  // ---------------- FFN in two 16-row halves -------------------------------
  for (int p = 0; p < 2; ++p) {
    // FFN1: H = relu(O1[p] @ w1 + b1)
    {
      f32x4 acc[4];
      #pragma unroll
      for (int c = 0; c < 4; ++c) {
        const float b = b1[(4 * w + c) * 16 + lr];
        acc[c] = (f32x4){b, b, b, b};
      }
      #pragma unroll
      for (int kk = 0; kk < 4; ++kk) {
        const bf16x8 a = *(const bf16x8*)(ldsh + O1B_H + (p * 16 + lr) * 136 + kk * 32 + lg * 8);
        #pragma unroll
        for (int c = 0; c < 4; ++c) {
          const int chunk = 96 + (4 * w + c) * 4 + kk;
          const bf16x8 b = *(const bf16x8*)(wpack + ((size_t)chunk * 64 + l) * 8);
          acc[c] = __builtin_amdgcn_mfma_f32_16x16x32_bf16(a, b, acc[c], 0, 0, 0);
        }
      }
      #pragma unroll
      for (int c = 0; c < 4; ++c) {
        const int col = (4 * w + c) * 16 + lr;
        #pragma unroll
        for (int e = 0; e < 4; ++e)
          ldsh[H_H + (lg * 4 + e) * 552 + col] = f2bf(fmaxf(acc[c][e], 0.0f));
      }
    }
    __syncthreads();

    // FFN2: O2 = H @ w2 + b2 + O1[p]
    {
      const int col = w * 16 + lr;
      const float b = b2[col];
      f32x4 acc = {b, b, b, b};
      #pragma unroll
      for (int kk = 0; kk < 16; ++kk) {
        const bf16x8 a = *(const bf16x8*)(ldsh + H_H + lr * 552 + kk * 32 + lg * 8);
        const int chunk = 224 + w * 16 + kk;
        const bf16x8 bb = *(const bf16x8*)(wpack + ((size_t)chunk * 64 + l) * 8);
        acc = __builtin_amdgcn_mfma_f32_16x16x32_bf16(a, bb, acc, 0, 0, 0);
      }
      #pragma unroll
      for (int e = 0; e < 4; ++e) {
        const int rl = lg * 4 + e;
        const float res = bf2f(ldsh[O1B_H + (p * 16 + rl) * 136 + col]);
        ldsf[O2F_F + rl * 132 + col] = acc[e] + res;
      }
    }
    __syncthreads();

    // LN2 + transposed store
    {
      const int r16 = t >> 5, sub = t & 31;
      const float4 v = *(const float4*)(ldsf + O2F_F + r16 * 132 + sub * 4);
      float sum = v.x + v.y + v.z + v.w;
      #pragma unroll
      for (int m = 1; m < 32; m <<= 1) sum += __shfl_xor(sum, m);
      const float mu = sum * (1.0f / 128.0f);
      float s2 = 0.0f;
      s2 += (v.x - mu) * (v.x - mu); s2 += (v.y - mu) * (v.y - mu);
      s2 += (v.z - mu) * (v.z - mu); s2 += (v.w - mu) * (v.w - mu);
      #pragma unroll
      for (int m = 1; m < 32; m <<= 1) s2 += __shfl_xor(s2, m);
      const float rstd = rsqrtf(s2 * (1.0f / 128.0f) + 1e-5f);
      const int c0 = sub * 4;
      float4 r;
      r.x = (v.x - mu) * rstd * ln2g[c0 + 0] + ln2b[c0 + 0];
      r.y = (v.y - mu) * rstd * ln2g[c0 + 1] + ln2b[c0 + 1];
      r.z = (v.z - mu) * rstd * ln2g[c0 + 2] + ln2b[c0 + 2];
      r.w = (v.w - mu) * rstd * ln2g[c0 + 3] + ln2b[c0 + 3];
      const int s = p * 16 + r16;
      *(float4*)(out + ((size_t)s * NN + n) * CC + c0) = r;
    }
    __syncthreads();
  }
}

// ---------------------------------------------------------------------------
// Fallback: round-1 fp32 kernel if ws too small for packing (never expected).
// ---------------------------------------------------------------------------
__global__ __launch_bounds__(512, 4) void fused_retention_block(
    const float* __restrict__ x,
    const float* __restrict__ wq, const float* __restrict__ bq,
    const float* __restrict__ wk, const float* __restrict__ bk,
    const float* __restrict__ wv, const float* __restrict__ bv,
    const float* __restrict__ ln1g, const float* __restrict__ ln1b,
    const float* __restrict__ w1, const float* __restrict__ b1,
    const float* __restrict__ w2, const float* __restrict__ b2,
    const float* __restrict__ ln2g, const float* __restrict__ ln2b,
    float* __restrict__ out)
{
  const int n = blockIdx.x;
  const int t = threadIdx.x;
  __shared__ float SM[3 * BS * QS];
  float* Qs = SM;
  float* Ks = SM + BS * QS;
  float* Vs = SM + 2 * BS * QS;
  {
    const int o4 = t & 31;
    const int sp = t >> 5;
    const float* xr0 = x + ((size_t)(2 * sp) * NN + n) * CC;
    const float* xr1 = xr0 + (size_t)NN * CC;
    for (int m = 0; m < 3; ++m) {
      const float* W  = (m == 0) ? wq : (m == 1) ? wk : wv;
      const float* bb = (m == 0) ? bq : (m == 1) ? bk : bv;
      float* O = SM + m * BS * QS;
      float b4[4];
      *(float4*)b4 = *(const float4*)(bb + o4 * 4);
      float a0[4] = {b4[0], b4[1], b4[2], b4[3]};
      float a1[4] = {b4[0], b4[1], b4[2], b4[3]};
      for (int c4 = 0; c4 < 32; ++c4) {
        float xa4[4], xb4[4];
        *(float4*)xa4 = *(const float4*)(xr0 + c4 * 4);
        *(float4*)xb4 = *(const float4*)(xr1 + c4 * 4);
        const float* wp = W + (c4 * 4) * CC + o4 * 4;
        #pragma unroll
        for (int j = 0; j < 4; ++j) {
          float w4[4];
          *(float4*)w4 = *(const float4*)(wp + j * CC);
          #pragma unroll
          for (int e = 0; e < 4; ++e) { a0[e] += xa4[j] * w4[e]; a1[e] += xb4[j] * w4[e]; }
        }
      }
      float* q0 = O + (2 * sp) * QS + o4 * 4;
      float* q1 = O + (2 * sp + 1) * QS + o4 * 4;
      #pragma unroll
      for (int e = 0; e < 4; ++e) { q0[e] = a0[e]; q1[e] = a1[e]; }
    }
  }
  __syncthreads();
  {
    const int tt = t & 255;
    const int s = tt >> 3;
    const int h = tt & 7;
    float* row = ((t < 256) ? Qs : Ks) + s * QS + h * DD;
    float v[DD];
    #pragma unroll
    for (int d = 0; d < DD; ++d) v[d] = row[d];
    #pragma unroll
    for (int d = 0; d < DD; ++d) {
      const int j = d >> 1;
      const float a = exp2f(-1.89824462565f * (float)j);
      const float ang = (float)s * a;
      const float sn = sinf(ang);
      const float cs = cosf(ang);
      const float rot = (d < 8) ? -v[2 * d + 1] : v[2 * (d - 8)];
      row[d] = v[d] * cs + rot * sn;
    }
  }
  __syncthreads();
  if (t < 256) {
    const int h = t >> 5;
    const int qi = t & 31;
    const float dec = log1pf(-exp2f(-(1.0f + 0.375f * (float)h)));
    float q[DD];
    const float* Qr = Qs + qi * QS + h * DD;
    #pragma unroll
    for (int d = 0; d < DD; ++d) q[d] = Qr[d];
    float sc[BS];
    float mx = -3.0e38f;
    #pragma unroll
    for (int jj = 0; jj < BS; ++jj) {
      const float* Kr = Ks + jj * QS + h * DD;
      float acc = fabsf((float)(qi - jj)) * dec;
      #pragma unroll
      for (int d = 0; d < DD; ++d) acc += q[d] * Kr[d];
      sc[jj] = acc;
      mx = fmaxf(mx, acc);
    }
    float sum = 0.0f;
    #pragma unroll
    for (int jj = 0; jj < BS; ++jj) { const float p = __expf(sc[jj] - mx); sc[jj] = p; sum += p; }
    const float inv = 1.0f / sum;
    float o[DD];
    #pragma unroll
    for (int d = 0; d < DD; ++d) o[d] = 0.0f;
    #pragma unroll
    for (int jj = 0; jj < BS; ++jj) {
      const float p = sc[jj] * inv;
      const float* Vr = Vs + jj * QS + h * DD;
      #pragma unroll
      for (int d = 0; d < DD; ++d) o[d] += p * Vr[d];
    }
    float* Od = Qs + qi * QS + h * DD;
    #pragma unroll
    for (int d = 0; d < DD; ++d) Od[d] = o[d];
  }
  __syncthreads();
  {
    const int row = t >> 4;
    const int sub = t & 15;
    float* Orow = Qs + row * QS + sub * 8;
    const float* xrow = x + ((size_t)row * NN + n) * CC + sub * 8;
    float v[8];
    #pragma unroll
    for (int i = 0; i < 8; ++i) v[i] = Orow[i] + xrow[i];
    float sum = 0.0f;
    #pragma unroll
    for (int i = 0; i < 8; ++i) sum += v[i];
    #pragma unroll
    for (int m = 1; m < 16; m <<= 1) sum += __shfl_xor(sum, m);
    const float mu = sum * (1.0f / 128.0f);
    float s2 = 0.0f;
    #pragma unroll
    for (int i = 0; i < 8; ++i) { const float d = v[i] - mu; s2 += d * d; }
    #pragma unroll
    for (int m = 1; m < 16; m <<= 1) s2 += __shfl_xor(s2, m);
    const float rstd = rsqrtf(s2 * (1.0f / 128.0f) + 1e-5f);
    #pragma unroll
    for (int i = 0; i < 8; ++i) {
      const int c = sub * 8 + i;
      Orow[i] = (v[i] - mu) * rstd * ln1g[c] + ln1b[c];
    }
  }
  __syncthreads();
  float* Hb = Ks;
  const int f4  = t & 127;
  const int sb4 = (t >> 7) * 4;
  const int o4f = t & 31;
  const int sF  = t >> 5;
  for (int p = 0; p < 2; ++p) {
    {
      float acc[4][4];
      float b14[4];
      *(float4*)b14 = *(const float4*)(b1 + f4 * 4);
      #pragma unroll
      for (int i = 0; i < 4; ++i)
        #pragma unroll
        for (int e = 0; e < 4; ++e) acc[i][e] = b14[e];
      const float* O1b = Qs + (p * 16 + sb4) * QS;
      for (int c = 0; c < CC; ++c) {
        float w4[4];
        *(float4*)w4 = *(const float4*)(w1 + c * FF + f4 * 4);
        #pragma unroll
        for (int i = 0; i < 4; ++i) {
          const float xv = O1b[i * QS + c];
          #pragma unroll
          for (int e = 0; e < 4; ++e) acc[i][e] += xv * w4[e];
        }
      }
      #pragma unroll
      for (int i = 0; i < 4; ++i) {
        float4 r;
        r.x = fmaxf(acc[i][0], 0.0f); r.y = fmaxf(acc[i][1], 0.0f);
        r.z = fmaxf(acc[i][2], 0.0f); r.w = fmaxf(acc[i][3], 0.0f);
        *(float4*)(Hb + (sb4 + i) * FF + f4 * 4) = r;
      }
    }
    __syncthreads();
    {
      const int s = p * 16 + sF;
      float acc[4];
      *(float4*)acc = *(const float4*)(b2 + o4f * 4);
      const float* hrow = Hb + sF * FF;
      for (int k = 0; k < FF; ++k) {
        const float hv = hrow[k];
        float w4[4];
        *(float4*)w4 = *(const float4*)(w2 + k * CC + o4f * 4);
        #pragma unroll
        for (int e = 0; e < 4; ++e) acc[e] += hv * w4[e];
      }
      const float* res = Qs + s * QS + o4f * 4;
      #pragma unroll
      for (int e = 0; e < 4; ++e) acc[e] += res[e];
      float sum = acc[0] + acc[1] + acc[2] + acc[3];
      #pragma unroll
      for (int m = 1; m < 32; m <<= 1) sum += __shfl_xor(sum, m);
      const float mu = sum * (1.0f / 128.0f);
      float s2 = 0.0f;
      #pragma unroll
      for (int e = 0; e < 4; ++e) { const float d = acc[e] - mu; s2 += d * d; }
      #pragma unroll
      for (int m = 1; m < 32; m <<= 1) s2 += __shfl_xor(s2, m);
      const float rstd = rsqrtf(s2 * (1.0f / 128.0f) + 1e-5f);
      float4 r;
      const int c0 = o4f * 4;
      r.x = (acc[0] - mu) * rstd * ln2g[c0 + 0] + ln2b[c0 + 0];
      r.y = (acc[1] - mu) * rstd * ln2g[c0 + 1] + ln2b[c0 + 1];
      r.z = (acc[2] - mu) * rstd * ln2g[c0 + 2] + ln2b[c0 + 2];
      r.w = (acc[3] - mu) * rstd * ln2g[c0 + 3] + ln2b[c0 + 3];
      *(float4*)(out + ((size_t)s * NN + n) * CC + c0) = r;
    }
    __syncthreads();
  }
}

extern "C" void kernel_launch(void* const* d_in, const int* in_sizes, int n_in,
                              void* d_out, int out_size, void* d_ws, size_t ws_size,
                              hipStream_t stream) {
  (void)in_sizes; (void)n_in; (void)out_size;
  const float* x    = (const float*)d_in[0];
  const float* wq   = (const float*)d_in[1];
  const float* bq_  = (const float*)d_in[2];
  const float* wk   = (const float*)d_in[3];
  const float* bk_  = (const float*)d_in[4];
  const float* wv   = (const float*)d_in[5];
  const float* bv_  = (const float*)d_in[6];
  const float* ln1g = (const float*)d_in[7];
  const float* ln1b = (const float*)d_in[8];
  const float* w1   = (const float*)d_in[9];
  const float* b1   = (const float*)d_in[10];
  const float* w2   = (const float*)d_in[11];
  const float* b2   = (const float*)d_in[12];
  const float* ln2g = (const float*)d_in[13];
  const float* ln2b = (const float*)d_in[14];
  float* outp = (float*)d_out;

  if (ws_size >= (size_t)22528 * 16) {
    unsigned short* wpack = (unsigned short*)d_ws;
    pack_weights<<<88, 256, 0, stream>>>(wq, wk, wv, w1, w2, wpack);
    fused_mfma<<<NN, 512, LDS_BYTES, stream>>>(
        x, bq_, bk_, bv_, ln1g, ln1b, b1, b2, ln2g, ln2b, wpack, outp);
  } else {
    fused_retention_block<<<NN, 512, 0, stream>>>(
        x, wq, bq_, wk, bk_, wv, bv_, ln1g, ln1b,
        w1, b1, w2, b2, ln2g, ln2b, outp);
  }
}

// Round 5
// 214.541 us; speedup vs baseline: 15.5303x; 1.2203x over previous
//
#include <hip/hip_runtime.h>

// Fused retention block, full-MFMA, round 5.
// grid = 8192 (one block per n), 512 threads = 8 waves (wave w = head w in attn).
// d_ws: [0,360448) packed bf16 weight fragments; [360448,364544) rot table f32x2[32][16].
// LDS pool 52736 B -> 3 blocks/CU. Offsets (bytes):
//   XB  [0,8704)      bf16[32][136] x tile        | FFN: O2 bf16[32][136]
//   QB  [8704,17408)  bf16[32][136] rot Q -> attn-out O | LN1 out O1B
//   KB  [17408,26112) bf16[32][136] rot K         | FFN: H bf16[32][552] @ [17408,52736)
//   VT  [26112,34304) bf16 per-head [16][32] V^T  | (H overlays)
//   P   [34304,52736) bf16 per-head [32][36]      | TAB f32x2[512] @ [34304,38400) in staging/QKV
// barriers: stage | QKV | attn | LN1 | FFN1 | FFN2 | (end)

#define NN 8192
#define BS 32
#define CC 128
#define HH 8
#define DD 16
#define FF 512
#define QS 129   // fp32 fallback stride

typedef __attribute__((ext_vector_type(8))) short bf16x8;
typedef __attribute__((ext_vector_type(4))) float f32x4;
typedef __attribute__((ext_vector_type(4))) unsigned int u32x4;
typedef __attribute__((ext_vector_type(2))) unsigned int u32x2;

#define XB_H 0
#define QB_H 4352
#define KB_H 8704
#define VT_H 13056
#define P_H 17152
#define P_HEAD 1152
#define P_STR 36
#define TAB_F 8576
#define O1B_H 4352
#define H_H 8704
#define O2_H 0
#define LDS_BYTES 52736

__device__ inline unsigned short f2bf(float f) {
  unsigned u = __builtin_bit_cast(unsigned, f);
  u = (u + 0x7FFFu + ((u >> 16) & 1u)) >> 16;
  return (unsigned short)u;
}
__device__ inline float bf2f(unsigned short h) {
  unsigned u = ((unsigned)h) << 16;
  return __builtin_bit_cast(float, u);
}

// ---------------------------------------------------------------------------
// Pack kernel: weights -> bf16 MFMA B-fragments + rot table in d_ws.
// ---------------------------------------------------------------------------
__global__ void pack_weights(const float* __restrict__ wq, const float* __restrict__ wk,
                             const float* __restrict__ wv, const float* __restrict__ w1,
                             const float* __restrict__ w2, unsigned short* __restrict__ outp)
{
  const int id = blockIdx.x * 256 + threadIdx.x;
  if (id >= 23040) return;
  if (id >= 22528) {  // rot table: (sin,cos) for (s,d)
    const int i = id - 22528;
    const int s = i >> 4, d = i & 15;
    const float a = exp2f(-1.89824462565f * (float)(d >> 1));
    const float ang = (float)s * a;
    float2* tab = (float2*)(outp + 180224);
    tab[i] = make_float2(sinf(ang), cosf(ang));
    return;
  }
  const int l = id & 63;
  const int chunk = id >> 6;
  const float* W; int ldw, colbase, k0;
  if (chunk < 96) {
    const int ct = chunk >> 2, kk = chunk & 3;
    W = (ct < 8) ? wq : (ct < 16) ? wk : wv;
    ldw = CC; colbase = (ct & 7) * 16 + (l & 15); k0 = kk * 32 + (l >> 4) * 8;
  } else if (chunk < 224) {
    const int c2 = chunk - 96, ct = c2 >> 2, kk = c2 & 3;
    W = w1; ldw = FF; colbase = ct * 16 + (l & 15); k0 = kk * 32 + (l >> 4) * 8;
  } else {
    const int c2 = chunk - 224, ct = c2 >> 4, kk = c2 & 15;
    W = w2; ldw = CC; colbase = ct * 16 + (l & 15); k0 = kk * 32 + (l >> 4) * 8;
  }
  unsigned int o[4];
  #pragma unroll
  for (int jj = 0; jj < 4; ++jj) {
    const unsigned lo = f2bf(W[(size_t)(k0 + 2 * jj) * ldw + colbase]);
    const unsigned hi = f2bf(W[(size_t)(k0 + 2 * jj + 1) * ldw + colbase]);
    o[jj] = lo | (hi << 16);
  }
  *(u32x4*)(outp + (size_t)id * 8) = (u32x4){o[0], o[1], o[2], o[3]};
}

__global__ __launch_bounds__(512, 6) void fused_mfma(
    const float* __restrict__ x,
    const float* __restrict__ bq, const float* __restrict__ bk, const float* __restrict__ bv,
    const float* __restrict__ ln1g, const float* __restrict__ ln1b,
    const float* __restrict__ b1, const float* __restrict__ b2,
    const float* __restrict__ ln2g, const float* __restrict__ ln2b,
    const unsigned short* __restrict__ wpack,
    const float2* __restrict__ rott,
    float* __restrict__ out)
{
  extern __shared__ char smem[];
  float* ldsf = (float*)smem;
  unsigned short* ldsh = (unsigned short*)smem;
  const int n = blockIdx.x;
  const int t = threadIdx.x;
  const int w = t >> 6;
  const int l = t & 63;
  const int lr = l & 15;
  const int lg = l >> 4;

  // ---------------- stage X -> bf16 LDS + rot table ------------------------
  {
    const int s = t >> 4, c0 = (t & 15) * 8;
    const float* xp = x + ((size_t)s * NN + n) * CC + c0;
    const float4 v0 = *(const float4*)xp;
    const float4 v1 = *(const float4*)(xp + 4);
    u32x4 pk;
    pk[0] = (unsigned)f2bf(v0.x) | ((unsigned)f2bf(v0.y) << 16);
    pk[1] = (unsigned)f2bf(v0.z) | ((unsigned)f2bf(v0.w) << 16);
    pk[2] = (unsigned)f2bf(v1.x) | ((unsigned)f2bf(v1.y) << 16);
    pk[3] = (unsigned)f2bf(v1.z) | ((unsigned)f2bf(v1.w) << 16);
    *(u32x4*)(ldsh + XB_H + s * 136 + c0) = pk;
    ((float2*)(ldsf + TAB_F))[t] = rott[t];
  }
  __syncthreads();

  // ---------------- QKV MFMA + fused rotary epilogue -----------------------
  {
    f32x4 acc[2][3];
    #pragma unroll
    for (int c = 0; c < 3; ++c) {
      const int ct = 3 * w + c;
      const int col = (ct & 7) * 16 + lr;
      const float* bb = (ct < 8) ? bq : (ct < 16) ? bk : bv;
      const float b = bb[col];
      acc[0][c] = (f32x4){b, b, b, b};
      acc[1][c] = acc[0][c];
    }
    #pragma unroll
    for (int kk = 0; kk < 4; ++kk) {
      const bf16x8 a0 = *(const bf16x8*)(ldsh + XB_H + lr * 136 + kk * 32 + lg * 8);
      const bf16x8 a1 = *(const bf16x8*)(ldsh + XB_H + (16 + lr) * 136 + kk * 32 + lg * 8);
      #pragma unroll
      for (int c = 0; c < 3; ++c) {
        const int ct = 3 * w + c;
        const bf16x8 b = *(const bf16x8*)(wpack + ((size_t)(ct * 4 + kk) * 64 + l) * 8);
        acc[0][c] = __builtin_amdgcn_mfma_f32_16x16x32_bf16(a0, b, acc[0][c], 0, 0, 0);
        acc[1][c] = __builtin_amdgcn_mfma_f32_16x16x32_bf16(a1, b, acc[1][c], 0, 0, 0);
      }
    }
    float sn[2][4], cs[2][4];
    if (3 * w < 16) {   // wave-uniform: only waves holding Q/K coltiles
      #pragma unroll
      for (int rt = 0; rt < 2; ++rt)
        #pragma unroll
        for (int e = 0; e < 4; ++e) {
          const int row = rt * 16 + lg * 4 + e;
          const float2 tc = ((const float2*)(ldsf + TAB_F))[row * 16 + lr];
          sn[rt][e] = tc.x;
          cs[rt][e] = tc.y;
        }
    }
    const int pd = (lr < 8) ? (2 * lr + 1) : (2 * lr - 16);
    const float sgn = (lr < 8) ? -1.0f : 1.0f;
    const int psrc = (l & 48) | pd;
    #pragma unroll
    for (int c = 0; c < 3; ++c) {
      const int ct = 3 * w + c;
      if (ct < 16) {
        const int dst = (ct < 8) ? QB_H : KB_H;
        const int colbase = (ct & 7) * 16;
        #pragma unroll
        for (int rt = 0; rt < 2; ++rt)
          #pragma unroll
          for (int e = 0; e < 4; ++e) {
            const float v = acc[rt][c][e];
            const float pv = __shfl(v, psrc);
            const float r = v * cs[rt][e] + sgn * pv * sn[rt][e];
            ldsh[dst + (rt * 16 + lg * 4 + e) * 136 + colbase + lr] = f2bf(r);
          }
      } else {
        // V^T: head hv, VT[hv][d=lr][s]
        const int hv = ct - 16;
        #pragma unroll
        for (int rt = 0; rt < 2; ++rt)
          #pragma unroll
          for (int e = 0; e < 4; ++e)
            ldsh[VT_H + hv * 512 + lr * 32 + rt * 16 + lg * 4 + e] = f2bf(acc[rt][c][e]);
      }
    }
  }
  __syncthreads();

  // ---------------- MFMA attention: wave w = head w ------------------------
  {
    const int h16 = w * 16;
    const float dec = log1pf(-exp2f(-(1.0f + 0.375f * (float)w)));
    const bf16x8 z = {};
    bf16x8 Ak[2], Bq[2];
    #pragma unroll
    for (int kt = 0; kt < 2; ++kt)
      Ak[kt] = (lg < 2) ? *(const bf16x8*)(ldsh + KB_H + (kt * 16 + lr) * 136 + h16 + lg * 8) : z;
    #pragma unroll
    for (int qt = 0; qt < 2; ++qt)
      Bq[qt] = (lg < 2) ? *(const bf16x8*)(ldsh + QB_H + (qt * 16 + lr) * 136 + h16 + lg * 8) : z;
    f32x4 accs[2][2];
    #pragma unroll
    for (int kt = 0; kt < 2; ++kt)
      #pragma unroll
      for (int qt = 0; qt < 2; ++qt) {
        #pragma unroll
        for (int e = 0; e < 4; ++e) {
          const int q = qt * 16 + lr;
          const int k = kt * 16 + lg * 4 + e;
          accs[kt][qt][e] = fabsf((float)(q - k)) * dec;
        }
        accs[kt][qt] = __builtin_amdgcn_mfma_f32_16x16x32_bf16(Ak[kt], Bq[qt], accs[kt][qt], 0, 0, 0);
      }
    unsigned short* Pl = ldsh + P_H + w * P_HEAD;
    #pragma unroll
    for (int qt = 0; qt < 2; ++qt) {
      float mx = accs[0][qt][0];
      #pragma unroll
      for (int kt = 0; kt < 2; ++kt)
        #pragma unroll
        for (int e = 0; e < 4; ++e) mx = fmaxf(mx, accs[kt][qt][e]);
      mx = fmaxf(mx, __shfl_xor(mx, 16));
      mx = fmaxf(mx, __shfl_xor(mx, 32));
      float p[2][4];
      float sm = 0.0f;
      #pragma unroll
      for (int kt = 0; kt < 2; ++kt)
        #pragma unroll
        for (int e = 0; e < 4; ++e) { p[kt][e] = __expf(accs[kt][qt][e] - mx); sm += p[kt][e]; }
      sm += __shfl_xor(sm, 16);
      sm += __shfl_xor(sm, 32);
      const float inv = 1.0f / sm;
      #pragma unroll
      for (int kt = 0; kt < 2; ++kt) {
        u32x2 pw;
        pw[0] = (unsigned)f2bf(p[kt][0] * inv) | ((unsigned)f2bf(p[kt][1] * inv) << 16);
        pw[1] = (unsigned)f2bf(p[kt][2] * inv) | ((unsigned)f2bf(p[kt][3] * inv) << 16);
        *(u32x2*)(Pl + (qt * 16 + lr) * P_STR + kt * 16 + lg * 4) = pw;
      }
    }
    // PV: B-frag = one vector read from V^T
    const bf16x8 Bv = *(const bf16x8*)(ldsh + VT_H + w * 512 + lr * 32 + lg * 8);
    #pragma unroll
    for (int qt = 0; qt < 2; ++qt) {
      const bf16x8 Ap = *(const bf16x8*)(Pl + (qt * 16 + lr) * P_STR + lg * 8);
      f32x4 z4 = {0.0f, 0.0f, 0.0f, 0.0f};
      const f32x4 o = __builtin_amdgcn_mfma_f32_16x16x32_bf16(Ap, Bv, z4, 0, 0, 0);
      #pragma unroll
      for (int e = 0; e < 4; ++e)
        ldsh[QB_H + (qt * 16 + lg * 4 + e) * 136 + h16 + lr] = f2bf(o[e]);
    }
  }
  __syncthreads();

  // ---------------- LN1(attn_out + x) -> O1 bf16 (in place over QB) --------
  {
    const int row = t >> 4, sub = t & 15;
    const unsigned short* Or = ldsh + QB_H + row * 136 + sub * 8;
    const unsigned short* Xr = ldsh + XB_H + row * 136 + sub * 8;
    float v[8];
    #pragma unroll
    for (int i = 0; i < 8; ++i) v[i] = bf2f(Or[i]) + bf2f(Xr[i]);
    float sum = 0.0f;
    #pragma unroll
    for (int i = 0; i < 8; ++i) sum += v[i];
    #pragma unroll
    for (int m = 1; m < 16; m <<= 1) sum += __shfl_xor(sum, m);
    const float mu = sum * (1.0f / 128.0f);
    float s2 = 0.0f;
    #pragma unroll
    for (int i = 0; i < 8; ++i) { const float d = v[i] - mu; s2 += d * d; }
    #pragma unroll
    for (int m = 1; m < 16; m <<= 1) s2 += __shfl_xor(s2, m);
    const float rstd = rsqrtf(s2 * (1.0f / 128.0f) + 1e-5f);
    u32x4 pk;
    #pragma unroll
    for (int i = 0; i < 4; ++i) {
      const int c = sub * 8 + 2 * i;
      const float e0 = (v[2 * i] - mu) * rstd * ln1g[c] + ln1b[c];
      const float e1 = (v[2 * i + 1] - mu) * rstd * ln1g[c + 1] + ln1b[c + 1];
      pk[i] = (unsigned)f2bf(e0) | ((unsigned)f2bf(e1) << 16);
    }
    *(u32x4*)(ldsh + O1B_H + row * 136 + sub * 8) = pk;
  }
  __syncthreads();

  // ---------------- FFN1: H(all 32 rows) = relu(O1 @ w1 + b1) --------------
  {
    f32x4 acc1[2][4];
    #pragma unroll
    for (int c = 0; c < 4; ++c) {
      const float b = b1[(4 * w + c) * 16 + lr];
      acc1[0][c] = (f32x4){b, b, b, b};
      acc1[1][c] = acc1[0][c];
    }
    #pragma unroll
    for (int kk = 0; kk < 4; ++kk) {
      const bf16x8 a0 = *(const bf16x8*)(ldsh + O1B_H + lr * 136 + kk * 32 + lg * 8);
      const bf16x8 a1 = *(const bf16x8*)(ldsh + O1B_H + (16 + lr) * 136 + kk * 32 + lg * 8);
      #pragma unroll
      for (int c = 0; c < 4; ++c) {
        const int chunk = 96 + (4 * w + c) * 4 + kk;
        const bf16x8 b = *(const bf16x8*)(wpack + ((size_t)chunk * 64 + l) * 8);
        acc1[0][c] = __builtin_amdgcn_mfma_f32_16x16x32_bf16(a0, b, acc1[0][c], 0, 0, 0);
        acc1[1][c] = __builtin_amdgcn_mfma_f32_16x16x32_bf16(a1, b, acc1[1][c], 0, 0, 0);
      }
    }
    #pragma unroll
    for (int p = 0; p < 2; ++p)
      #pragma unroll
      for (int c = 0; c < 4; ++c) {
        const int col = (4 * w + c) * 16 + lr;
        #pragma unroll
        for (int e = 0; e < 4; ++e)
          ldsh[H_H + (p * 16 + lg * 4 + e) * 552 + col] = f2bf(fmaxf(acc1[p][c][e], 0.0f));
      }
  }
  __syncthreads();

  // ---------------- FFN2: O2(all) = H @ w2 + b2 + O1 -----------------------
  {
    const int col = w * 16 + lr;
    const float b = b2[col];
    f32x4 acc2[2];
    acc2[0] = (f32x4){b, b, b, b};
    acc2[1] = acc2[0];
    #pragma unroll
    for (int kk = 0; kk < 16; ++kk) {
      const bf16x8 a0 = *(const bf16x8*)(ldsh + H_H + lr * 552 + kk * 32 + lg * 8);
      const bf16x8 a1 = *(const bf16x8*)(ldsh + H_H + (16 + lr) * 552 + kk * 32 + lg * 8);
      const int chunk = 224 + w * 16 + kk;
      const bf16x8 bb = *(const bf16x8*)(wpack + ((size_t)chunk * 64 + l) * 8);
      acc2[0] = __builtin_amdgcn_mfma_f32_16x16x32_bf16(a0, bb, acc2[0], 0, 0, 0);
      acc2[1] = __builtin_amdgcn_mfma_f32_16x16x32_bf16(a1, bb, acc2[1], 0, 0, 0);
    }
    #pragma unroll
    for (int p = 0; p < 2; ++p)
      #pragma unroll
      for (int e = 0; e < 4; ++e) {
        const int srow = p * 16 + lg * 4 + e;
        const float res = bf2f(ldsh[O1B_H + srow * 136 + col]);
        ldsh[O2_H + srow * 136 + col] = f2bf(acc2[p][e] + res);
      }
  }
  __syncthreads();

  // ---------------- LN2 (32 rows at once) + transposed store ---------------
  {
    const int row = t >> 4, sub = t & 15;
    const unsigned short* Or = ldsh + O2_H + row * 136 + sub * 8;
    float v[8];
    #pragma unroll
    for (int i = 0; i < 8; ++i) v[i] = bf2f(Or[i]);
    float sum = 0.0f;
    #pragma unroll
    for (int i = 0; i < 8; ++i) sum += v[i];
    #pragma unroll
    for (int m = 1; m < 16; m <<= 1) sum += __shfl_xor(sum, m);
    const float mu = sum * (1.0f / 128.0f);
    float s2 = 0.0f;
    #pragma unroll
    for (int i = 0; i < 8; ++i) { const float d = v[i] - mu; s2 += d * d; }
    #pragma unroll
    for (int m = 1; m < 16; m <<= 1) s2 += __shfl_xor(s2, m);
    const float rstd = rsqrtf(s2 * (1.0f / 128.0f) + 1e-5f);
    const int c0 = sub * 8;
    float4 r0, r1;
    r0.x = (v[0] - mu) * rstd * ln2g[c0 + 0] + ln2b[c0 + 0];
    r0.y = (v[1] - mu) * rstd * ln2g[c0 + 1] + ln2b[c0 + 1];
    r0.z = (v[2] - mu) * rstd * ln2g[c0 + 2] + ln2b[c0 + 2];
    r0.w = (v[3] - mu) * rstd * ln2g[c0 + 3] + ln2b[c0 + 3];
    r1.x = (v[4] - mu) * rstd * ln2g[c0 + 4] + ln2b[c0 + 4];
    r1.y = (v[5] - mu) * rstd * ln2g[c0 + 5] + ln2b[c0 + 5];
    r1.z = (v[6] - mu) * rstd * ln2g[c0 + 6] + ln2b[c0 + 6];
    r1.w = (v[7] - mu) * rstd * ln2g[c0 + 7] + ln2b[c0 + 7];
    float* op = out + ((size_t)row * NN + n) * CC + c0;
    *(float4*)op = r0;
    *(float4*)(op + 4) = r1;
  }
}

// ---------------------------------------------------------------------------
// Fallback: round-1 fp32 kernel if ws too small for packing (never expected).
// ---------------------------------------------------------------------------
__global__ __launch_bounds__(512, 4) void fused_retention_block(
    const float* __restrict__ x,
    const float* __restrict__ wq, const float* __restrict__ bq,
    const float* __restrict__ wk, const float* __restrict__ bk,
    const float* __restrict__ wv, const float* __restrict__ bv,
    const float* __restrict__ ln1g, const float* __restrict__ ln1b,
    const float* __restrict__ w1, const float* __restrict__ b1,
    const float* __restrict__ w2, const float* __restrict__ b2,
    const float* __restrict__ ln2g, const float* __restrict__ ln2b,
    float* __restrict__ out)
{
  const int n = blockIdx.x;
  const int t = threadIdx.x;
  __shared__ float SM[3 * BS * QS];
  float* Qs = SM;
  float* Ks = SM + BS * QS;
  float* Vs = SM + 2 * BS * QS;
  {
    const int o4 = t & 31;
    const int sp = t >> 5;
    const float* xr0 = x + ((size_t)(2 * sp) * NN + n) * CC;
    const float* xr1 = xr0 + (size_t)NN * CC;
    for (int m = 0; m < 3; ++m) {
      const float* W  = (m == 0) ? wq : (m == 1) ? wk : wv;
      const float* bb = (m == 0) ? bq : (m == 1) ? bk : bv;
      float* O = SM + m * BS * QS;
      float b4[4];
      *(float4*)b4 = *(const float4*)(bb + o4 * 4);
      float a0[4] = {b4[0], b4[1], b4[2], b4[3]};
      float a1[4] = {b4[0], b4[1], b4[2], b4[3]};
      for (int c4 = 0; c4 < 32; ++c4) {
        float xa4[4], xb4[4];
        *(float4*)xa4 = *(const float4*)(xr0 + c4 * 4);
        *(float4*)xb4 = *(const float4*)(xr1 + c4 * 4);
        const float* wp = W + (c4 * 4) * CC + o4 * 4;
        #pragma unroll
        for (int j = 0; j < 4; ++j) {
          float w4[4];
          *(float4*)w4 = *(const float4*)(wp + j * CC);
          #pragma unroll
          for (int e = 0; e < 4; ++e) { a0[e] += xa4[j] * w4[e]; a1[e] += xb4[j] * w4[e]; }
        }
      }
      float* q0 = O + (2 * sp) * QS + o4 * 4;
      float* q1 = O + (2 * sp + 1) * QS + o4 * 4;
      #pragma unroll
      for (int e = 0; e < 4; ++e) { q0[e] = a0[e]; q1[e] = a1[e]; }
    }
  }
  __syncthreads();
  {
    const int tt = t & 255;
    const int s = tt >> 3;
    const int h = tt & 7;
    float* row = ((t < 256) ? Qs : Ks) + s * QS + h * DD;
    float v[DD];
    #pragma unroll
    for (int d = 0; d < DD; ++d) v[d] = row[d];
    #pragma unroll
    for (int d = 0; d < DD; ++d) {
      const int j = d >> 1;
      const float a = exp2f(-1.89824462565f * (float)j);
      const float ang = (float)s * a;
      const float sn = sinf(ang);
      const float cs = cosf(ang);
      const float rot = (d < 8) ? -v[2 * d + 1] : v[2 * (d - 8)];
      row[d] = v[d] * cs + rot * sn;
    }
  }
  __syncthreads();
  if (t < 256) {
    const int h = t >> 5;
    const int qi = t & 31;
    const float dec = log1pf(-exp2f(-(1.0f + 0.375f * (float)h)));
    float q[DD];
    const float* Qr = Qs + qi * QS + h * DD;
    #pragma unroll
    for (int d = 0; d < DD; ++d) q[d] = Qr[d];
    float sc[BS];
    float mx = -3.0e38f;
    #pragma unroll
    for (int jj = 0; jj < BS; ++jj) {
      const float* Kr = Ks + jj * QS + h * DD;
      float acc = fabsf((float)(qi - jj)) * dec;
      #pragma unroll
      for (int d = 0; d < DD; ++d) acc += q[d] * Kr[d];
      sc[jj] = acc;
      mx = fmaxf(mx, acc);
    }
    float sum = 0.0f;
    #pragma unroll
    for (int jj = 0; jj < BS; ++jj) { const float p = __expf(sc[jj] - mx); sc[jj] = p; sum += p; }
    const float inv = 1.0f / sum;
    float o[DD];
    #pragma unroll
    for (int d = 0; d < DD; ++d) o[d] = 0.0f;
    #pragma unroll
    for (int jj = 0; jj < BS; ++jj) {
      const float p = sc[jj] * inv;
      const float* Vr = Vs + jj * QS + h * DD;
      #pragma unroll
      for (int d = 0; d < DD; ++d) o[d] += p * Vr[d];
    }
    float* Od = Qs + qi * QS + h * DD;
    #pragma unroll
    for (int d = 0; d < DD; ++d) Od[d] = o[d];
  }
  __syncthreads();
  {
    const int row = t >> 4;
    const int sub = t & 15;
    float* Orow = Qs + row * QS + sub * 8;
    const float* xrow = x + ((size_t)row * NN + n) * CC + sub * 8;
    float v[8];
    #pragma unroll
    for (int i = 0; i < 8; ++i) v[i] = Orow[i] + xrow[i];
    float sum = 0.0f;
    #pragma unroll
    for (int i = 0; i < 8; ++i) sum += v[i];
    #pragma unroll
    for (int m = 1; m < 16; m <<= 1) sum += __shfl_xor(sum, m);
    const float mu = sum * (1.0f / 128.0f);
    float s2 = 0.0f;
    #pragma unroll
    for (int i = 0; i < 8; ++i) { const float d = v[i] - mu; s2 += d * d; }
    #pragma unroll
    for (int m = 1; m < 16; m <<= 1) s2 += __shfl_xor(s2, m);
    const float rstd = rsqrtf(s2 * (1.0f / 128.0f) + 1e-5f);
    #pragma unroll
    for (int i = 0; i < 8; ++i) {
      const int c = sub * 8 + i;
      Orow[i] = (v[i] - mu) * rstd * ln1g[c] + ln1b[c];
    }
  }
  __syncthreads();
  float* Hb = Ks;
  const int f4  = t & 127;
  const int sb4 = (t >> 7) * 4;
  const int o4f = t & 31;
  const int sF  = t >> 5;
  for (int p = 0; p < 2; ++p) {
    {
      float acc[4][4];
      float b14[4];
      *(float4*)b14 = *(const float4*)(b1 + f4 * 4);
      #pragma unroll
      for (int i = 0; i < 4; ++i)
        #pragma unroll
        for (int e = 0; e < 4; ++e) acc[i][e] = b14[e];
      const float* O1b = Qs + (p * 16 + sb4) * QS;
      for (int c = 0; c < CC; ++c) {
        float w4[4];
        *(float4*)w4 = *(const float4*)(w1 + c * FF + f4 * 4);
        #pragma unroll
        for (int i = 0; i < 4; ++i) {
          const float xv = O1b[i * QS + c];
          #pragma unroll
          for (int e = 0; e < 4; ++e) acc[i][e] += xv * w4[e];
        }
      }
      #pragma unroll
      for (int i = 0; i < 4; ++i) {
        float4 r;
        r.x = fmaxf(acc[i][0], 0.0f); r.y = fmaxf(acc[i][1], 0.0f);
        r.z = fmaxf(acc[i][2], 0.0f); r.w = fmaxf(acc[i][3], 0.0f);
        *(float4*)(Hb + (sb4 + i) * FF + f4 * 4) = r;
      }
    }
    __syncthreads();
    {
      const int s = p * 16 + sF;
      float acc[4];
      *(float4*)acc = *(const float4*)(b2 + o4f * 4);
      const float* hrow = Hb + sF * FF;
      for (int k = 0; k < FF; ++k) {
        const float hv = hrow[k];
        float w4[4];
        *(float4*)w4 = *(const float4*)(w2 + k * CC + o4f * 4);
        #pragma unroll
        for (int e = 0; e < 4; ++e) acc[e] += hv * w4[e];
      }
      const float* res = Qs + s * QS + o4f * 4;
      #pragma unroll
      for (int e = 0; e < 4; ++e) acc[e] += res[e];
      float sum = acc[0] + acc[1] + acc[2] + acc[3];
      #pragma unroll
      for (int m = 1; m < 32; m <<= 1) sum += __shfl_xor(sum, m);
      const float mu = sum * (1.0f / 128.0f);
      float s2 = 0.0f;
      #pragma unroll
      for (int e = 0; e < 4; ++e) { const float d = acc[e] - mu; s2 += d * d; }
      #pragma unroll
      for (int m = 1; m < 32; m <<= 1) s2 += __shfl_xor(s2, m);
      const float rstd = rsqrtf(s2 * (1.0f / 128.0f) + 1e-5f);
      float4 r;
      const int c0 = o4f * 4;
      r.x = (acc[0] - mu) * rstd * ln2g[c0 + 0] + ln2b[c0 + 0];
      r.y = (acc[1] - mu) * rstd * ln2g[c0 + 1] + ln2b[c0 + 1];
      r.z = (acc[2] - mu) * rstd * ln2g[c0 + 2] + ln2b[c0 + 2];
      r.w = (acc[3] - mu) * rstd * ln2g[c0 + 3] + ln2b[c0 + 3];
      *(float4*)(out + ((size_t)s * NN + n) * CC + c0) = r;
    }
    __syncthreads();
  }
}

extern "C" void kernel_launch(void* const* d_in, const int* in_sizes, int n_in,
                              void* d_out, int out_size, void* d_ws, size_t ws_size,
                              hipStream_t stream) {
  (void)in_sizes; (void)n_in; (void)out_size;
  const float* x    = (const float*)d_in[0];
  const float* wq   = (const float*)d_in[1];
  const float* bq_  = (const float*)d_in[2];
  const float* wk   = (const float*)d_in[3];
  const float* bk_  = (const float*)d_in[4];
  const float* wv   = (const float*)d_in[5];
  const float* bv_  = (const float*)d_in[6];
  const float* ln1g = (const float*)d_in[7];
  const float* ln1b = (const float*)d_in[8];
  const float* w1   = (const float*)d_in[9];
  const float* b1   = (const float*)d_in[10];
  const float* w2   = (const float*)d_in[11];
  const float* b2   = (const float*)d_in[12];
  const float* ln2g = (const float*)d_in[13];
  const float* ln2b = (const float*)d_in[14];
  float* outp = (float*)d_out;

  if (ws_size >= (size_t)364544) {
    unsigned short* wpack = (unsigned short*)d_ws;
    const float2* rott = (const float2*)((const char*)d_ws + 360448);
    pack_weights<<<90, 256, 0, stream>>>(wq, wk, wv, w1, w2, wpack);
    fused_mfma<<<NN, 512, LDS_BYTES, stream>>>(
        x, bq_, bk_, bv_, ln1g, ln1b, b1, b2, ln2g, ln2b, wpack, rott, outp);
  } else {
    fused_retention_block<<<NN, 512, 0, stream>>>(
        x, wq, bq_, wk, bk_, wv, bv_, ln1g, ln1b,
        w1, b1, w2, b2, ln2g, ln2b, outp);
  }
}